// Round 5
// baseline (386.670 us; speedup 1.0000x reference)
//
#include <hip/hip_runtime.h>
#include <hip/hip_bf16.h>

// Mamba block on MI355X. B=2, L=512, d_model=1024, d_inner=2048, d_state=64, K=4.
// Pipeline:
//   transpose x3 : weights -> bf16 [N][K]
//   gemm1 : xzf[1024][4096] = x(f32, cvt in stage) @ Wt1^T   (MFMA bf16)
//   conv  : xc = silu(causal depthwise conv(xs)) f32 + bf16 copy
//   gemm2 : split-K x16 partials of xcb @ Wt2^T -> P
//   reduce_bc : P -> BT[n][tok], CT[n][tok] (f32) + dtr[tok]
//   pack  : uaT[d][tok]={dt,dt*x} f32x2 (LDS transpose); ug2[tok][d]=bf16x2{D*x,g}
//   scan  : wave per (b,d), lane=n; stores RAW p (gating deferred) + final state
//   gate  : ybb[tok][d] = bf16((praw + D*x) * g)
//   gemm3 : split-K x4 partials of ybb @ Wt3^T -> Pg ; reduce_z -> out

#define N_TOK   1024
#define SEQ_L   512
#define D_MODEL 1024
#define D_INNER 2048
#define D_STATE 64
#define D_XZ    4096
#define N_XP    129

typedef __attribute__((ext_vector_type(8))) short bf16x8;
typedef __attribute__((ext_vector_type(4))) float f32x4;

__device__ __forceinline__ unsigned short f2bf(float f) {
  __hip_bfloat16 h = __float2bfloat16(f);
  return *reinterpret_cast<unsigned short*>(&h);
}
__device__ __forceinline__ float bf16lo(unsigned int u) { return __uint_as_float(u << 16); }
__device__ __forceinline__ float bf16hi(unsigned int u) { return __uint_as_float(u & 0xffff0000u); }

// ---------- transpose + f32->bf16 convert: dst[C][R] = bf16(src[R][C]) ----------
__global__ __launch_bounds__(256) void transpose_bf16(
    const float* __restrict__ src, __hip_bfloat16* __restrict__ dst, int R, int C) {
  __shared__ float t[64][65];
  int c0 = blockIdx.x * 64, r0 = blockIdx.y * 64;
  int tc = threadIdx.x & 63, tg = threadIdx.x >> 6;
#pragma unroll
  for (int i = 0; i < 16; ++i) {
    int r = r0 + tg + i * 4, c = c0 + tc;
    t[tg + i * 4][tc] = (r < R && c < C) ? src[(size_t)r * C + c] : 0.f;
  }
  __syncthreads();
#pragma unroll
  for (int i = 0; i < 16; ++i) {
    int c = c0 + tg + i * 4, r = r0 + tc;
    if (c < C && r < R) dst[(size_t)c * R + r] = __float2bfloat16(t[tc][tg + i * 4]);
  }
}

// ---------- MFMA bf16 TN GEMM (full-K): C[M][N] = A[M][K] @ Bt[N][K]^T ----------
template<int A_F32>
__global__ __launch_bounds__(256) void gemm_bf16_tn(
    const void* __restrict__ Av, const __hip_bfloat16* __restrict__ Bt,
    float* __restrict__ C, int M, int N, int K) {
  __shared__ short As[128][40];  // rows padded to 80 B
  __shared__ short Bs[128][40];
  const int brow = blockIdx.y * 128, bcol = blockIdx.x * 128;
  const int tid = threadIdx.x;
  const int lane = tid & 63, wave = tid >> 6;
  const int wm = wave >> 1, wn = wave & 1;
  const int l15 = lane & 15, lk = lane >> 4;
  f32x4 acc[4][4] = {};
  for (int k0 = 0; k0 < K; k0 += 32) {
#pragma unroll
    for (int i = 0; i < 2; ++i) {
      int v = tid + i * 256;
      int r = v >> 2, kc = (v & 3) * 8;
      if (A_F32) {
        const float* Af = (const float*)Av;
        float4 f0 = *(const float4*)&Af[(size_t)(brow + r) * K + k0 + kc];
        float4 f1 = *(const float4*)&Af[(size_t)(brow + r) * K + k0 + kc + 4];
        bf16x8 h;
        h[0] = (short)f2bf(f0.x); h[1] = (short)f2bf(f0.y);
        h[2] = (short)f2bf(f0.z); h[3] = (short)f2bf(f0.w);
        h[4] = (short)f2bf(f1.x); h[5] = (short)f2bf(f1.y);
        h[6] = (short)f2bf(f1.z); h[7] = (short)f2bf(f1.w);
        *(bf16x8*)((char*)&As[0][0] + r * 80 + kc * 2) = h;
      } else {
        const __hip_bfloat16* Ab = (const __hip_bfloat16*)Av;
        *(bf16x8*)((char*)&As[0][0] + r * 80 + kc * 2) =
            *(const bf16x8*)&Ab[(size_t)(brow + r) * K + k0 + kc];
      }
      *(bf16x8*)((char*)&Bs[0][0] + r * 80 + kc * 2) =
          *(const bf16x8*)&Bt[(size_t)(bcol + r) * K + k0 + kc];
    }
    __syncthreads();
    bf16x8 af[4], bfr[4];
#pragma unroll
    for (int m = 0; m < 4; ++m)
      af[m] = *(const bf16x8*)((const char*)&As[0][0] + (wm * 64 + m * 16 + l15) * 80 + lk * 16);
#pragma unroll
    for (int n = 0; n < 4; ++n)
      bfr[n] = *(const bf16x8*)((const char*)&Bs[0][0] + (wn * 64 + n * 16 + l15) * 80 + lk * 16);
#pragma unroll
    for (int m = 0; m < 4; ++m)
#pragma unroll
      for (int n = 0; n < 4; ++n)
        acc[m][n] = __builtin_amdgcn_mfma_f32_16x16x32_bf16(af[m], bfr[n], acc[m][n], 0, 0, 0);
    __syncthreads();
  }
#pragma unroll
  for (int m = 0; m < 4; ++m) {
    int row = brow + wm * 64 + m * 16 + lk * 4;
#pragma unroll
    for (int n = 0; n < 4; ++n) {
      int col = bcol + wn * 64 + n * 16 + l15;
#pragma unroll
      for (int r = 0; r < 4; ++r)
        C[(size_t)(row + r) * N + col] = acc[m][n][r];
    }
  }
}

// ---------- split-K MFMA GEMM: P[z][M][N] partials, chunk = kchunk ----------
__global__ __launch_bounds__(256) void gemm_splitk(
    const __hip_bfloat16* __restrict__ A, const __hip_bfloat16* __restrict__ Bt,
    float* __restrict__ P, int M, int N, int K, int kchunk) {
  __shared__ short As[128][40];
  __shared__ short Bs[128][40];
  const int brow = blockIdx.y * 128, bcol = blockIdx.x * 128;
  const int kbase = blockIdx.z * kchunk;
  const int tid = threadIdx.x;
  const int lane = tid & 63, wave = tid >> 6;
  const int wm = wave >> 1, wn = wave & 1;
  const int l15 = lane & 15, lk = lane >> 4;
  f32x4 acc[4][4] = {};
  for (int k0 = kbase; k0 < kbase + kchunk; k0 += 32) {
#pragma unroll
    for (int i = 0; i < 2; ++i) {
      int v = tid + i * 256;
      int r = v >> 2, kc = (v & 3) * 8;
      *(bf16x8*)((char*)&As[0][0] + r * 80 + kc * 2) =
          *(const bf16x8*)&A[(size_t)(brow + r) * K + k0 + kc];
      bf16x8 bv = {};
      if ((bcol + r) < N)
        bv = *(const bf16x8*)&Bt[(size_t)(bcol + r) * K + k0 + kc];
      *(bf16x8*)((char*)&Bs[0][0] + r * 80 + kc * 2) = bv;
    }
    __syncthreads();
    bf16x8 af[4], bfr[4];
#pragma unroll
    for (int m = 0; m < 4; ++m)
      af[m] = *(const bf16x8*)((const char*)&As[0][0] + (wm * 64 + m * 16 + l15) * 80 + lk * 16);
#pragma unroll
    for (int n = 0; n < 4; ++n)
      bfr[n] = *(const bf16x8*)((const char*)&Bs[0][0] + (wn * 64 + n * 16 + l15) * 80 + lk * 16);
#pragma unroll
    for (int m = 0; m < 4; ++m)
#pragma unroll
      for (int n = 0; n < 4; ++n)
        acc[m][n] = __builtin_amdgcn_mfma_f32_16x16x32_bf16(af[m], bfr[n], acc[m][n], 0, 0, 0);
    __syncthreads();
  }
  float* Pz = P + (size_t)blockIdx.z * M * N;
#pragma unroll
  for (int m = 0; m < 4; ++m) {
    int row = brow + wm * 64 + m * 16 + lk * 4;
#pragma unroll
    for (int n = 0; n < 4; ++n) {
      int col = bcol + wn * 64 + n * 16 + l15;
      if (col < N) {
#pragma unroll
        for (int r = 0; r < 4; ++r)
          Pz[(size_t)(row + r) * N + col] = acc[m][n][r];
      }
    }
  }
}

// ---------- reduce Z partials elementwise (vectorized x4) ----------
template<int Z>
__global__ __launch_bounds__(256) void reduce_z(
    const float* __restrict__ P, float* __restrict__ out, int n) {
  int i = (blockIdx.x * 256 + threadIdx.x) * 4;
  if (i >= n) return;
  float4 s = *(const float4*)&P[i];
#pragma unroll
  for (int z = 1; z < Z; ++z) {
    float4 v = *(const float4*)&P[(size_t)z * n + i];
    s.x += v.x; s.y += v.y; s.z += v.z; s.w += v.w;
  }
  *(float4*)&out[i] = s;
}

// ---------- reduce partials -> BT/CT (f32, [n][tok]) + dtr[tok] ----------
__global__ __launch_bounds__(256) void reduce_bc(
    const float* __restrict__ P, float* __restrict__ BT,
    float* __restrict__ CT, float* __restrict__ dtr) {
  int tok = blockIdx.x * 4 + (threadIdx.x >> 6);
  int n = threadIdx.x & 63;
  const float* p0 = P + (size_t)tok * N_XP + n;
  float sB = 0.f, sC = 0.f;
#pragma unroll
  for (int z = 0; z < 16; ++z) {
    sB += p0[(size_t)z * N_TOK * N_XP];
    sC += p0[(size_t)z * N_TOK * N_XP + 64];
  }
  BT[(size_t)n * N_TOK + tok] = sB;
  CT[(size_t)n * N_TOK + tok] = sC;
  if (n == 0) {
    float sd = 0.f;
    const float* pd = P + (size_t)tok * N_XP + 128;
#pragma unroll
    for (int z = 0; z < 16; ++z) sd += pd[(size_t)z * N_TOK * N_XP];
    dtr[tok] = sd;
  }
}

// ---------- causal depthwise conv (K=4) + SiLU ----------
__global__ __launch_bounds__(256) void conv_silu_kernel(
    const float* __restrict__ xz, const float* __restrict__ cw,
    const float* __restrict__ cb, float* __restrict__ xc,
    __hip_bfloat16* __restrict__ xcb) {
  int idx = blockIdx.x * 256 + threadIdx.x;
  int c = idx & (D_INNER - 1);
  int tok = idx >> 11;
  int l = tok & (SEQ_L - 1);
  float acc = cb[c];
#pragma unroll
  for (int k = 0; k < 4; ++k) {
    int ll = l - 3 + k;
    if (ll >= 0) acc = fmaf(xz[(size_t)(tok - 3 + k) * D_XZ + c], cw[c * 4 + k], acc);
  }
  float v = acc / (1.f + __expf(-acc));
  xc[idx] = v;
  xcb[idx] = __float2bfloat16(v);
}

// ---------- pack: uaT[d][tok]={dt,dt*x} (LDS transpose); ug2[tok][d]={Dx,g} ----------
__global__ __launch_bounds__(256) void pack_kernel(
    const float* __restrict__ xzf, const float* __restrict__ xc,
    const float* __restrict__ dtr, const float* __restrict__ dt_w,
    const float* __restrict__ dt_b, const float* __restrict__ Dv,
    float2* __restrict__ uaT, unsigned int* __restrict__ ug2) {
  __shared__ float2 la[64][33];
  int tok0 = blockIdx.x * 32, d0 = blockIdx.y * 64;
  int t = threadIdx.x;
  int dl = t & 63, tc = t >> 6;
  int d = d0 + dl;
  float w = dt_w[d], bb = dt_b[d], Dd = Dv[d];
#pragma unroll
  for (int p = 0; p < 8; ++p) {
    int tl = p * 4 + tc;
    int tok = tok0 + tl;
    float xt = xc[(size_t)tok * D_INNER + d];
    float z = xzf[(size_t)tok * D_XZ + D_INNER + d];
    float dt = dtr[tok] * w + bb;
    dt = (dt > 20.f) ? dt : log1pf(__expf(dt));
    la[dl][tl] = make_float2(dt, dt * xt);
    float g = z / (1.f + __expf(-z));
    ug2[(size_t)tok * D_INNER + d] =
        (unsigned int)f2bf(Dd * xt) | ((unsigned int)f2bf(g) << 16);
  }
  __syncthreads();
  int tl2 = t & 31, dg = t >> 5;
#pragma unroll
  for (int q = 0; q < 8; ++q) {
    int dl2 = q * 8 + dg;
    uaT[(size_t)(d0 + dl2) * N_TOK + tok0 + tl2] = la[dl2][tl2];
  }
}

// ---------- gate: ybb = bf16((praw + Dx) * g) ----------
__global__ __launch_bounds__(256) void gate_kernel(
    const float* __restrict__ praw, const unsigned int* __restrict__ ug2,
    __hip_bfloat16* __restrict__ ybb) {
  int i = (blockIdx.x * 256 + threadIdx.x) * 4;
  float4 p = *(const float4*)&praw[i];
  uint4 u = *(const uint4*)&ug2[i];
  unsigned short o[4];
  o[0] = f2bf((p.x + bf16lo(u.x)) * bf16hi(u.x));
  o[1] = f2bf((p.y + bf16lo(u.y)) * bf16hi(u.y));
  o[2] = f2bf((p.z + bf16lo(u.z)) * bf16hi(u.z));
  o[3] = f2bf((p.w + bf16lo(u.w)) * bf16hi(u.w));
  *(uint2*)&ybb[i] = make_uint2((unsigned)o[0] | ((unsigned)o[1] << 16),
                                (unsigned)o[2] | ((unsigned)o[3] << 16));
}

// ---------- DPP wave-64 sum: result in lane 63 ----------
template<int CTRL>
__device__ __forceinline__ float dppadd(float v) {
  int t = __builtin_amdgcn_update_dpp(0, __float_as_int(v), CTRL, 0xF, 0xF, true);
  return v + __int_as_float(t);
}
__device__ __forceinline__ float wave_sum64(float v) {
  v = dppadd<0x111>(v);  // row_shr:1
  v = dppadd<0x112>(v);  // row_shr:2
  v = dppadd<0x114>(v);  // row_shr:4
  v = dppadd<0x118>(v);  // row_shr:8
  v = dppadd<0x142>(v);  // row_bcast:15
  v = dppadd<0x143>(v);  // row_bcast:31
  return v;
}

// ---------- selective scan: wave per (b,d), lane=n; raw p out ----------
#define TOK(dtv, dtxv, bv, cv, j) { \
    float dA = __expf((dtv) * a); \
    s = fmaf(dA, s, (dtxv) * (bv)); \
    pp[j] = wave_sum64(s * (cv)); }

#define COMPUTE(S, lb) { float pp[8]; \
  TOK(S##u0.x, S##u0.y, S##bb0.x, S##cc0.x, 0) \
  TOK(S##u0.z, S##u0.w, S##bb0.y, S##cc0.y, 1) \
  TOK(S##u1.x, S##u1.y, S##bb0.z, S##cc0.z, 2) \
  TOK(S##u1.z, S##u1.w, S##bb0.w, S##cc0.w, 3) \
  TOK(S##u2.x, S##u2.y, S##bb1.x, S##cc1.x, 4) \
  TOK(S##u2.z, S##u2.w, S##bb1.y, S##cc1.y, 5) \
  TOK(S##u3.x, S##u3.y, S##bb1.z, S##cc1.z, 6) \
  TOK(S##u3.z, S##u3.w, S##bb1.w, S##cc1.w, 7) \
  if (lane == 63) { \
    _Pragma("unroll") \
    for (int j = 0; j < 8; ++j) po[(size_t)((lb) + j) * D_INNER] = pp[j]; } }

#define LOADBLK(S, lb) \
  S##u0 = ua[(lb) / 2]; S##u1 = ua[(lb) / 2 + 1]; \
  S##u2 = ua[(lb) / 2 + 2]; S##u3 = ua[(lb) / 2 + 3]; \
  S##bb0 = Bt4[(lb) / 4]; S##bb1 = Bt4[(lb) / 4 + 1]; \
  S##cc0 = Ct4[(lb) / 4]; S##cc1 = Ct4[(lb) / 4 + 1];

__global__ __launch_bounds__(256) void scan_kernel(
    const float2* __restrict__ uaT, const float* __restrict__ BT,
    const float* __restrict__ CT, const float* __restrict__ A_log,
    float* __restrict__ praw, float* __restrict__ state_out) {
  int wid = (blockIdx.x * 256 + threadIdx.x) >> 6;
  int lane = threadIdx.x & 63;
  int b = wid >> 11, d = wid & (D_INNER - 1);
  float a = -__expf(A_log[d * D_STATE + lane]);
  float s = 0.f;
  const int tok0 = b * SEQ_L;
  const float4* ua = (const float4*)(uaT + (size_t)d * N_TOK + tok0);
  const float4* Bt4 = (const float4*)(BT + (size_t)lane * N_TOK + tok0);
  const float4* Ct4 = (const float4*)(CT + (size_t)lane * N_TOK + tok0);
  float* po = praw + (size_t)tok0 * D_INNER + d;
  float4 Au0, Au1, Au2, Au3, Bu0, Bu1, Bu2, Bu3;
  float4 Abb0, Abb1, Bbb0, Bbb1, Acc0, Acc1, Bcc0, Bcc1;
  LOADBLK(A, 0)
#pragma unroll 1
  for (int l = 0; l < SEQ_L; l += 16) {
    LOADBLK(B, l + 8)
    COMPUTE(A, l)
    if (l + 16 < SEQ_L) { LOADBLK(A, l + 16) }
    COMPUTE(B, l + 8)
  }
  state_out[(size_t)wid * D_STATE + lane] = s;
}

extern "C" void kernel_launch(void* const* d_in, const int* in_sizes, int n_in,
                              void* d_out, int out_size, void* d_ws, size_t ws_size,
                              hipStream_t stream) {
  const float* x         = (const float*)d_in[0];
  const float* in_proj_w = (const float*)d_in[1];
  const float* conv_w    = (const float*)d_in[2];
  const float* conv_b    = (const float*)d_in[3];
  const float* x_proj_w  = (const float*)d_in[4];
  const float* dt_w      = (const float*)d_in[5];
  const float* dt_b      = (const float*)d_in[6];
  const float* A_log     = (const float*)d_in[7];
  const float* Dvec      = (const float*)d_in[8];
  const float* out_proj_w= (const float*)d_in[9];

  char* w = (char*)d_ws;
  __hip_bfloat16* Wt1 = (__hip_bfloat16*)w; w += (size_t)D_XZ * D_MODEL * 2;      // 8 MB
  __hip_bfloat16* Wt2 = (__hip_bfloat16*)w; w += (size_t)N_XP * D_INNER * 2;      // 516 KB
  __hip_bfloat16* Wt3 = (__hip_bfloat16*)w; w += (size_t)D_MODEL * D_INNER * 2;   // 4 MB
  float*          xzf = (float*)w;          w += (size_t)N_TOK * D_XZ * 4;        // 16 MB
  float*          xc  = (float*)w;          w += (size_t)N_TOK * D_INNER * 4;     // 8 MB
  __hip_bfloat16* xcb = (__hip_bfloat16*)w; w += (size_t)N_TOK * D_INNER * 2;     // 4 MB
  float*          P   = (float*)w;          w += (size_t)16 * N_TOK * N_XP * 4;   // 8.45 MB
  float*          BT  = (float*)w;          w += (size_t)D_STATE * N_TOK * 4;     // 256 KB
  float*          CT  = (float*)w;          w += (size_t)D_STATE * N_TOK * 4;     // 256 KB
  float*          dtr = (float*)w;          w += (size_t)N_TOK * 4;               // 4 KB
  float2*         uaT = (float2*)w;         w += (size_t)D_INNER * N_TOK * 8;     // 16 MB
  unsigned int*   ug2 = (unsigned int*)w;   w += (size_t)N_TOK * D_INNER * 4;     // 8 MB
  // aliases (lifetimes verified):
  float*          praw = P;                      // 8 MB <= P's 8.45 MB; P dead after reduce_bc
  __hip_bfloat16* ybb  = xcb;                    // 4 MB; xcb dead after gemm2
  float*          Pg   = xzf;                    // 16 MB; xzf dead after pack

  float* out       = (float*)d_out;
  float* state_out = out + (size_t)N_TOK * D_MODEL;

  dim3 blk(256);
  transpose_bf16<<<dim3(D_XZ / 64, D_MODEL / 64), blk, 0, stream>>>(in_proj_w, Wt1, D_MODEL, D_XZ);
  transpose_bf16<<<dim3((N_XP + 63) / 64, D_INNER / 64), blk, 0, stream>>>(x_proj_w, Wt2, D_INNER, N_XP);
  transpose_bf16<<<dim3(D_MODEL / 64, D_INNER / 64), blk, 0, stream>>>(out_proj_w, Wt3, D_INNER, D_MODEL);
  // 1) xz = x @ in_proj_w
  gemm_bf16_tn<1><<<dim3(D_XZ / 128, N_TOK / 128), blk, 0, stream>>>(x, Wt1, xzf, N_TOK, D_XZ, D_MODEL);
  // 2) conv + silu
  conv_silu_kernel<<<(N_TOK * D_INNER) / 256, blk, 0, stream>>>(xzf, conv_w, conv_b, xc, xcb);
  // 3) xp partials: split-K x16 (kchunk=128)
  gemm_splitk<<<dim3((N_XP + 127) / 128, N_TOK / 128, 16), blk, 0, stream>>>(xcb, Wt2, P, N_TOK, N_XP, D_INNER, 128);
  // 4) reduce -> BT/CT (f32) + dtr
  reduce_bc<<<N_TOK / 4, blk, 0, stream>>>(P, BT, CT, dtr);
  // 5) pack streams
  pack_kernel<<<dim3(N_TOK / 32, D_INNER / 64), blk, 0, stream>>>(xzf, xc, dtr, dt_w, dt_b, Dvec, uaT, ug2);
  // 6) scan (raw p out; gating deferred)
  scan_kernel<<<(2 * D_INNER * 64) / 256, blk, 0, stream>>>(uaT, BT, CT, A_log, praw, state_out);
  // 7) gate
  gate_kernel<<<(N_TOK * D_INNER) / 1024, blk, 0, stream>>>(praw, ug2, ybb);
  // 8) out = y @ out_proj_w : split-K x4 (kchunk=512) + reduce
  gemm_splitk<<<dim3(D_MODEL / 128, N_TOK / 128, 4), blk, 0, stream>>>(ybb, Wt3, Pg, N_TOK, D_MODEL, D_INNER, 512);
  reduce_z<4><<<(N_TOK * D_MODEL) / 1024, blk, 0, stream>>>(Pg, out, N_TOK * D_MODEL);
}

// Round 6
// 328.369 us; speedup vs baseline: 1.1775x; 1.1775x over previous
//
#include <hip/hip_runtime.h>
#include <hip/hip_bf16.h>

// Mamba block on MI355X. B=2, L=512, d_model=1024, d_inner=2048, d_state=64, K=4.
// Pipeline:
//   transpose x3 : weights -> bf16 [N][K]
//   gemm1 : xzf[1024][4096] = x(f32, cvt in stage) @ Wt1^T   (MFMA bf16)
//   conv  : xc = silu(causal depthwise conv(xs)) f32 + bf16 copy
//   gemm2 : split-K x16 partials of xcb @ Wt2^T -> P
//   reduce_bc : P -> bcP[tok][n] (packed bf16 {B,C}) + dtr[tok]
//   pack  : uaT[d][tok]={dt,dt*x} f32x2 ; ug2[tok][d]=bf16x2{D*x,g}
//   scan  : 3-pass chunked (4 chunks x 128 toks):
//           partial (P=prod dA, local state) -> combine (chain chunks, state_out)
//           -> final (full recurrence + DPP reduce, praw[d][tok])
//   gate  : LDS-transpose, ybb[tok][d] = bf16((praw + D*x) * g)
//   gemm3 : split-K x4 partials of ybb @ Wt3^T -> Pg ; reduce_z -> out

#define N_TOK   1024
#define SEQ_L   512
#define D_MODEL 1024
#define D_INNER 2048
#define D_STATE 64
#define D_XZ    4096
#define N_XP    129

typedef __attribute__((ext_vector_type(8))) short bf16x8;
typedef __attribute__((ext_vector_type(4))) float f32x4;

__device__ __forceinline__ unsigned short f2bf(float f) {
  __hip_bfloat16 h = __float2bfloat16(f);
  return *reinterpret_cast<unsigned short*>(&h);
}
__device__ __forceinline__ float bf16lo(unsigned int u) { return __uint_as_float(u << 16); }
__device__ __forceinline__ float bf16hi(unsigned int u) { return __uint_as_float(u & 0xffff0000u); }

// ---------- transpose + f32->bf16 convert: dst[C][R] = bf16(src[R][C]) ----------
__global__ __launch_bounds__(256) void transpose_bf16(
    const float* __restrict__ src, __hip_bfloat16* __restrict__ dst, int R, int C) {
  __shared__ float t[64][65];
  int c0 = blockIdx.x * 64, r0 = blockIdx.y * 64;
  int tc = threadIdx.x & 63, tg = threadIdx.x >> 6;
#pragma unroll
  for (int i = 0; i < 16; ++i) {
    int r = r0 + tg + i * 4, c = c0 + tc;
    t[tg + i * 4][tc] = (r < R && c < C) ? src[(size_t)r * C + c] : 0.f;
  }
  __syncthreads();
#pragma unroll
  for (int i = 0; i < 16; ++i) {
    int c = c0 + tg + i * 4, r = r0 + tc;
    if (c < C && r < R) dst[(size_t)c * R + r] = __float2bfloat16(t[tc][tg + i * 4]);
  }
}

// ---------- MFMA bf16 TN GEMM (full-K): C[M][N] = A[M][K] @ Bt[N][K]^T ----------
template<int A_F32>
__global__ __launch_bounds__(256) void gemm_bf16_tn(
    const void* __restrict__ Av, const __hip_bfloat16* __restrict__ Bt,
    float* __restrict__ C, int M, int N, int K) {
  __shared__ short As[128][40];  // rows padded to 80 B
  __shared__ short Bs[128][40];
  const int brow = blockIdx.y * 128, bcol = blockIdx.x * 128;
  const int tid = threadIdx.x;
  const int lane = tid & 63, wave = tid >> 6;
  const int wm = wave >> 1, wn = wave & 1;
  const int l15 = lane & 15, lk = lane >> 4;
  f32x4 acc[4][4] = {};
  for (int k0 = 0; k0 < K; k0 += 32) {
#pragma unroll
    for (int i = 0; i < 2; ++i) {
      int v = tid + i * 256;
      int r = v >> 2, kc = (v & 3) * 8;
      if (A_F32) {
        const float* Af = (const float*)Av;
        float4 f0 = *(const float4*)&Af[(size_t)(brow + r) * K + k0 + kc];
        float4 f1 = *(const float4*)&Af[(size_t)(brow + r) * K + k0 + kc + 4];
        bf16x8 h;
        h[0] = (short)f2bf(f0.x); h[1] = (short)f2bf(f0.y);
        h[2] = (short)f2bf(f0.z); h[3] = (short)f2bf(f0.w);
        h[4] = (short)f2bf(f1.x); h[5] = (short)f2bf(f1.y);
        h[6] = (short)f2bf(f1.z); h[7] = (short)f2bf(f1.w);
        *(bf16x8*)((char*)&As[0][0] + r * 80 + kc * 2) = h;
      } else {
        const __hip_bfloat16* Ab = (const __hip_bfloat16*)Av;
        *(bf16x8*)((char*)&As[0][0] + r * 80 + kc * 2) =
            *(const bf16x8*)&Ab[(size_t)(brow + r) * K + k0 + kc];
      }
      *(bf16x8*)((char*)&Bs[0][0] + r * 80 + kc * 2) =
          *(const bf16x8*)&Bt[(size_t)(bcol + r) * K + k0 + kc];
    }
    __syncthreads();
    bf16x8 af[4], bfr[4];
#pragma unroll
    for (int m = 0; m < 4; ++m)
      af[m] = *(const bf16x8*)((const char*)&As[0][0] + (wm * 64 + m * 16 + l15) * 80 + lk * 16);
#pragma unroll
    for (int n = 0; n < 4; ++n)
      bfr[n] = *(const bf16x8*)((const char*)&Bs[0][0] + (wn * 64 + n * 16 + l15) * 80 + lk * 16);
#pragma unroll
    for (int m = 0; m < 4; ++m)
#pragma unroll
      for (int n = 0; n < 4; ++n)
        acc[m][n] = __builtin_amdgcn_mfma_f32_16x16x32_bf16(af[m], bfr[n], acc[m][n], 0, 0, 0);
    __syncthreads();
  }
#pragma unroll
  for (int m = 0; m < 4; ++m) {
    int row = brow + wm * 64 + m * 16 + lk * 4;
#pragma unroll
    for (int n = 0; n < 4; ++n) {
      int col = bcol + wn * 64 + n * 16 + l15;
#pragma unroll
      for (int r = 0; r < 4; ++r)
        C[(size_t)(row + r) * N + col] = acc[m][n][r];
    }
  }
}

// ---------- split-K MFMA GEMM: P[z][M][N] partials, chunk = kchunk ----------
__global__ __launch_bounds__(256) void gemm_splitk(
    const __hip_bfloat16* __restrict__ A, const __hip_bfloat16* __restrict__ Bt,
    float* __restrict__ P, int M, int N, int K, int kchunk) {
  __shared__ short As[128][40];
  __shared__ short Bs[128][40];
  const int brow = blockIdx.y * 128, bcol = blockIdx.x * 128;
  const int kbase = blockIdx.z * kchunk;
  const int tid = threadIdx.x;
  const int lane = tid & 63, wave = tid >> 6;
  const int wm = wave >> 1, wn = wave & 1;
  const int l15 = lane & 15, lk = lane >> 4;
  f32x4 acc[4][4] = {};
  for (int k0 = kbase; k0 < kbase + kchunk; k0 += 32) {
#pragma unroll
    for (int i = 0; i < 2; ++i) {
      int v = tid + i * 256;
      int r = v >> 2, kc = (v & 3) * 8;
      *(bf16x8*)((char*)&As[0][0] + r * 80 + kc * 2) =
          *(const bf16x8*)&A[(size_t)(brow + r) * K + k0 + kc];
      bf16x8 bv = {};
      if ((bcol + r) < N)
        bv = *(const bf16x8*)&Bt[(size_t)(bcol + r) * K + k0 + kc];
      *(bf16x8*)((char*)&Bs[0][0] + r * 80 + kc * 2) = bv;
    }
    __syncthreads();
    bf16x8 af[4], bfr[4];
#pragma unroll
    for (int m = 0; m < 4; ++m)
      af[m] = *(const bf16x8*)((const char*)&As[0][0] + (wm * 64 + m * 16 + l15) * 80 + lk * 16);
#pragma unroll
    for (int n = 0; n < 4; ++n)
      bfr[n] = *(const bf16x8*)((const char*)&Bs[0][0] + (wn * 64 + n * 16 + l15) * 80 + lk * 16);
#pragma unroll
    for (int m = 0; m < 4; ++m)
#pragma unroll
      for (int n = 0; n < 4; ++n)
        acc[m][n] = __builtin_amdgcn_mfma_f32_16x16x32_bf16(af[m], bfr[n], acc[m][n], 0, 0, 0);
    __syncthreads();
  }
  float* Pz = P + (size_t)blockIdx.z * M * N;
#pragma unroll
  for (int m = 0; m < 4; ++m) {
    int row = brow + wm * 64 + m * 16 + lk * 4;
#pragma unroll
    for (int n = 0; n < 4; ++n) {
      int col = bcol + wn * 64 + n * 16 + l15;
      if (col < N) {
#pragma unroll
        for (int r = 0; r < 4; ++r)
          Pz[(size_t)(row + r) * N + col] = acc[m][n][r];
      }
    }
  }
}

// ---------- reduce Z partials elementwise (vectorized x4) ----------
template<int Z>
__global__ __launch_bounds__(256) void reduce_z(
    const float* __restrict__ P, float* __restrict__ out, int n) {
  int i = (blockIdx.x * 256 + threadIdx.x) * 4;
  if (i >= n) return;
  float4 s = *(const float4*)&P[i];
#pragma unroll
  for (int z = 1; z < Z; ++z) {
    float4 v = *(const float4*)&P[(size_t)z * n + i];
    s.x += v.x; s.y += v.y; s.z += v.z; s.w += v.w;
  }
  *(float4*)&out[i] = s;
}

// ---------- reduce partials -> bcP[tok][n] (packed bf16 {B,C}) + dtr[tok] ----------
__global__ __launch_bounds__(256) void reduce_bc(
    const float* __restrict__ P, unsigned int* __restrict__ bcP,
    float* __restrict__ dtr) {
  int tok = blockIdx.x * 4 + (threadIdx.x >> 6);
  int n = threadIdx.x & 63;
  const float* p0 = P + (size_t)tok * N_XP + n;
  float sB = 0.f, sC = 0.f;
#pragma unroll
  for (int z = 0; z < 16; ++z) {
    sB += p0[(size_t)z * N_TOK * N_XP];
    sC += p0[(size_t)z * N_TOK * N_XP + 64];
  }
  bcP[(size_t)tok * D_STATE + n] = (unsigned)f2bf(sB) | ((unsigned)f2bf(sC) << 16);
  if (n == 0) {
    float sd = 0.f;
    const float* pd = P + (size_t)tok * N_XP + 128;
#pragma unroll
    for (int z = 0; z < 16; ++z) sd += pd[(size_t)z * N_TOK * N_XP];
    dtr[tok] = sd;
  }
}

// ---------- causal depthwise conv (K=4) + SiLU ----------
__global__ __launch_bounds__(256) void conv_silu_kernel(
    const float* __restrict__ xz, const float* __restrict__ cw,
    const float* __restrict__ cb, float* __restrict__ xc,
    __hip_bfloat16* __restrict__ xcb) {
  int idx = blockIdx.x * 256 + threadIdx.x;
  int c = idx & (D_INNER - 1);
  int tok = idx >> 11;
  int l = tok & (SEQ_L - 1);
  float acc = cb[c];
#pragma unroll
  for (int k = 0; k < 4; ++k) {
    int ll = l - 3 + k;
    if (ll >= 0) acc = fmaf(xz[(size_t)(tok - 3 + k) * D_XZ + c], cw[c * 4 + k], acc);
  }
  float v = acc / (1.f + __expf(-acc));
  xc[idx] = v;
  xcb[idx] = __float2bfloat16(v);
}

// ---------- pack: uaT[d][tok]={dt,dt*x} (LDS transpose); ug2[tok][d]={Dx,g} ----------
__global__ __launch_bounds__(256) void pack_kernel(
    const float* __restrict__ xzf, const float* __restrict__ xc,
    const float* __restrict__ dtr, const float* __restrict__ dt_w,
    const float* __restrict__ dt_b, const float* __restrict__ Dv,
    float2* __restrict__ uaT, unsigned int* __restrict__ ug2) {
  __shared__ float2 la[64][33];
  int tok0 = blockIdx.x * 32, d0 = blockIdx.y * 64;
  int t = threadIdx.x;
  int dl = t & 63, tc = t >> 6;
  int d = d0 + dl;
  float w = dt_w[d], bb = dt_b[d], Dd = Dv[d];
#pragma unroll
  for (int p = 0; p < 8; ++p) {
    int tl = p * 4 + tc;
    int tok = tok0 + tl;
    float xt = xc[(size_t)tok * D_INNER + d];
    float z = xzf[(size_t)tok * D_XZ + D_INNER + d];
    float dt = dtr[tok] * w + bb;
    dt = (dt > 20.f) ? dt : log1pf(__expf(dt));
    la[dl][tl] = make_float2(dt, dt * xt);
    float g = z / (1.f + __expf(-z));
    ug2[(size_t)tok * D_INNER + d] =
        (unsigned int)f2bf(Dd * xt) | ((unsigned int)f2bf(g) << 16);
  }
  __syncthreads();
  int tl2 = t & 31, dg = t >> 5;
#pragma unroll
  for (int q = 0; q < 8; ++q) {
    int dl2 = q * 8 + dg;
    uaT[(size_t)(d0 + dl2) * N_TOK + tok0 + tl2] = la[dl2][tl2];
  }
}

// ---------- gate w/ LDS transpose: ybb[tok][d] = bf16((praw[d][tok] + Dx)*g) ----------
__global__ __launch_bounds__(256) void gate_kernel(
    const float* __restrict__ praw, const unsigned int* __restrict__ ug2,
    __hip_bfloat16* __restrict__ ybb) {
  __shared__ float tile[64][65];
  int tok0 = blockIdx.x * 64, d0 = blockIdx.y * 64;
  int t = threadIdx.x, tc = t & 63, tg = t >> 6;
#pragma unroll
  for (int i = 0; i < 16; ++i) {
    int dl = tg + i * 4;
    tile[dl][tc] = praw[(size_t)(d0 + dl) * N_TOK + tok0 + tc];
  }
  __syncthreads();
#pragma unroll
  for (int i = 0; i < 16; ++i) {
    int tl = tg + i * 4;
    size_t idx = (size_t)(tok0 + tl) * D_INNER + d0 + tc;
    unsigned u = ug2[idx];
    float v = (tile[tc][tl] + bf16lo(u)) * bf16hi(u);
    ybb[idx] = __float2bfloat16(v);
  }
}

// ---------- DPP wave-64 sum: result in lane 63 ----------
template<int CTRL>
__device__ __forceinline__ float dppadd(float v) {
  int t = __builtin_amdgcn_update_dpp(0, __float_as_int(v), CTRL, 0xF, 0xF, true);
  return v + __int_as_float(t);
}
__device__ __forceinline__ float wave_sum64(float v) {
  v = dppadd<0x111>(v);  // row_shr:1
  v = dppadd<0x112>(v);  // row_shr:2
  v = dppadd<0x114>(v);  // row_shr:4
  v = dppadd<0x118>(v);  // row_shr:8
  v = dppadd<0x142>(v);  // row_bcast:15
  v = dppadd<0x143>(v);  // row_bcast:31
  return v;
}

// ---------- pass A: per-chunk decay product + local final state ----------
#define PTOK(dtv, dtxv, bu) { \
    float dA = __expf((dtv) * a); \
    Pr *= dA; \
    s = fmaf(dA, s, (dtxv) * bf16lo(bu)); }

__global__ __launch_bounds__(256) void scan_partial(
    const float2* __restrict__ uaT, const unsigned int* __restrict__ bcP,
    const float* __restrict__ A_log, float* __restrict__ Pp,
    float* __restrict__ sloc) {
  int wid = (blockIdx.x * 256 + threadIdx.x) >> 6;   // ((b*2048+d)*4+ch)
  int lane = threadIdx.x & 63;
  int ch = wid & 3, d = (wid >> 2) & (D_INNER - 1), b = wid >> 13;
  float a = -__expf(A_log[d * D_STATE + lane]);
  int tok0 = b * SEQ_L + ch * 128;
  const float4* ua = (const float4*)(uaT + (size_t)d * N_TOK + tok0);
  const unsigned* bp = bcP + (size_t)tok0 * D_STATE + lane;
  float s = 0.f, Pr = 1.f;
#pragma unroll 2
  for (int l = 0; l < 128; l += 8) {
    float4 u0 = ua[l / 2], u1 = ua[l / 2 + 1], u2 = ua[l / 2 + 2], u3 = ua[l / 2 + 3];
    unsigned b0 = bp[(l + 0) * 64], b1 = bp[(l + 1) * 64];
    unsigned b2 = bp[(l + 2) * 64], b3 = bp[(l + 3) * 64];
    unsigned b4 = bp[(l + 4) * 64], b5 = bp[(l + 5) * 64];
    unsigned b6 = bp[(l + 6) * 64], b7 = bp[(l + 7) * 64];
    PTOK(u0.x, u0.y, b0) PTOK(u0.z, u0.w, b1)
    PTOK(u1.x, u1.y, b2) PTOK(u1.z, u1.w, b3)
    PTOK(u2.x, u2.y, b4) PTOK(u2.z, u2.w, b5)
    PTOK(u3.x, u3.y, b6) PTOK(u3.z, u3.w, b7)
  }
  Pp[(size_t)wid * D_STATE + lane] = Pr;
  sloc[(size_t)wid * D_STATE + lane] = s;
}

// ---------- pass B: chain chunk states; write s_in per chunk + final state ----------
__global__ __launch_bounds__(256) void scan_combine(
    const float* __restrict__ Pp, const float* __restrict__ sloc,
    float* __restrict__ sin, float* __restrict__ state_out) {
  int wid = (blockIdx.x * 256 + threadIdx.x) >> 6;  // 0..4095 = b*2048+d
  int lane = threadIdx.x & 63;
  const float* Pw = Pp + (size_t)wid * 256;
  const float* sw = sloc + (size_t)wid * 256;
  float* si = sin + (size_t)wid * 256;
  float s = 0.f;
  si[lane] = 0.f;
#pragma unroll
  for (int c = 0; c < 4; ++c) {
    s = fmaf(Pw[c * 64 + lane], s, sw[c * 64 + lane]);
    if (c < 3) si[(c + 1) * 64 + lane] = s;
  }
  state_out[(size_t)wid * D_STATE + lane] = s;
}

// ---------- pass C: full recurrence + reduce, starting from s_in ----------
#define FTOK(dtv, dtxv, bu, pj) { \
    float dA = __expf((dtv) * a); \
    s = fmaf(dA, s, (dtxv) * bf16lo(bu)); \
    pj = wave_sum64(s * bf16hi(bu)); }

__global__ __launch_bounds__(256) void scan_final(
    const float2* __restrict__ uaT, const unsigned int* __restrict__ bcP,
    const float* __restrict__ A_log, const float* __restrict__ sin,
    float* __restrict__ praw) {
  int wid = (blockIdx.x * 256 + threadIdx.x) >> 6;   // ((b*2048+d)*4+ch)
  int lane = threadIdx.x & 63;
  int ch = wid & 3, d = (wid >> 2) & (D_INNER - 1), b = wid >> 13;
  float a = -__expf(A_log[d * D_STATE + lane]);
  int tok0 = b * SEQ_L + ch * 128;
  const float4* ua = (const float4*)(uaT + (size_t)d * N_TOK + tok0);
  const unsigned* bp = bcP + (size_t)tok0 * D_STATE + lane;
  float* po = praw + (size_t)d * N_TOK + tok0;
  float s = sin[(size_t)wid * D_STATE + lane];
#pragma unroll 2
  for (int l = 0; l < 128; l += 8) {
    float4 u0 = ua[l / 2], u1 = ua[l / 2 + 1], u2 = ua[l / 2 + 2], u3 = ua[l / 2 + 3];
    unsigned b0 = bp[(l + 0) * 64], b1 = bp[(l + 1) * 64];
    unsigned b2 = bp[(l + 2) * 64], b3 = bp[(l + 3) * 64];
    unsigned b4 = bp[(l + 4) * 64], b5 = bp[(l + 5) * 64];
    unsigned b6 = bp[(l + 6) * 64], b7 = bp[(l + 7) * 64];
    float p0, p1, p2, p3, p4, p5, p6, p7;
    FTOK(u0.x, u0.y, b0, p0) FTOK(u0.z, u0.w, b1, p1)
    FTOK(u1.x, u1.y, b2, p2) FTOK(u1.z, u1.w, b3, p3)
    FTOK(u2.x, u2.y, b4, p4) FTOK(u2.z, u2.w, b5, p5)
    FTOK(u3.x, u3.y, b6, p6) FTOK(u3.z, u3.w, b7, p7)
    if (lane == 63) {
      *(float4*)(po + l) = make_float4(p0, p1, p2, p3);
      *(float4*)(po + l + 4) = make_float4(p4, p5, p6, p7);
    }
  }
}

extern "C" void kernel_launch(void* const* d_in, const int* in_sizes, int n_in,
                              void* d_out, int out_size, void* d_ws, size_t ws_size,
                              hipStream_t stream) {
  const float* x         = (const float*)d_in[0];
  const float* in_proj_w = (const float*)d_in[1];
  const float* conv_w    = (const float*)d_in[2];
  const float* conv_b    = (const float*)d_in[3];
  const float* x_proj_w  = (const float*)d_in[4];
  const float* dt_w      = (const float*)d_in[5];
  const float* dt_b      = (const float*)d_in[6];
  const float* A_log     = (const float*)d_in[7];
  const float* Dvec      = (const float*)d_in[8];
  const float* out_proj_w= (const float*)d_in[9];

  char* w = (char*)d_ws;
  __hip_bfloat16* Wt1 = (__hip_bfloat16*)w; w += (size_t)D_XZ * D_MODEL * 2;      // 8 MB
  __hip_bfloat16* Wt2 = (__hip_bfloat16*)w; w += (size_t)N_XP * D_INNER * 2;      // 516 KB
  __hip_bfloat16* Wt3 = (__hip_bfloat16*)w; w += (size_t)D_MODEL * D_INNER * 2;   // 4 MB
  float*          xzf = (float*)w;          w += (size_t)N_TOK * D_XZ * 4;        // 16 MB
  float*          xc  = (float*)w;          w += (size_t)N_TOK * D_INNER * 4;     // 8 MB
  __hip_bfloat16* xcb = (__hip_bfloat16*)w; w += (size_t)N_TOK * D_INNER * 2;     // 4 MB
  float*          P   = (float*)w;          w += (size_t)16 * N_TOK * N_XP * 4;   // 8.45 MB
  unsigned int*   bcP = (unsigned int*)w;   w += (size_t)N_TOK * D_STATE * 4;     // 256 KB
  float*          dtr = (float*)w;          w += (size_t)N_TOK * 4;               // 4 KB
  float2*         uaT = (float2*)w;         w += (size_t)D_INNER * N_TOK * 8;     // 16 MB
  unsigned int*   ug2 = (unsigned int*)w;   w += (size_t)N_TOK * D_INNER * 4;     // 8 MB
  // aliases (lifetimes):
  float*          praw = P;            // 8 MB <= 8.45 MB; P dead after reduce_bc
  __hip_bfloat16* ybb  = xcb;          // 4 MB; xcb dead after gemm2
  float*          Pp   = xzf;          // chunk arrays live in xzf (dead after pack)
  float*          sloc = Pp + (size_t)4096 * 256;     // +4 MB
  float*          sin  = sloc + (size_t)4096 * 256;   // +4 MB
  float*          Pg   = xzf;          // 16 MB; chunk arrays dead before gemm3

  float* out       = (float*)d_out;
  float* state_out = out + (size_t)N_TOK * D_MODEL;

  dim3 blk(256);
  transpose_bf16<<<dim3(D_XZ / 64, D_MODEL / 64), blk, 0, stream>>>(in_proj_w, Wt1, D_MODEL, D_XZ);
  transpose_bf16<<<dim3((N_XP + 63) / 64, D_INNER / 64), blk, 0, stream>>>(x_proj_w, Wt2, D_INNER, N_XP);
  transpose_bf16<<<dim3(D_MODEL / 64, D_INNER / 64), blk, 0, stream>>>(out_proj_w, Wt3, D_INNER, D_MODEL);
  // 1) xz = x @ in_proj_w
  gemm_bf16_tn<1><<<dim3(D_XZ / 128, N_TOK / 128), blk, 0, stream>>>(x, Wt1, xzf, N_TOK, D_XZ, D_MODEL);
  // 2) conv + silu
  conv_silu_kernel<<<(N_TOK * D_INNER) / 256, blk, 0, stream>>>(xzf, conv_w, conv_b, xc, xcb);
  // 3) xp partials: split-K x16 (kchunk=128)
  gemm_splitk<<<dim3((N_XP + 127) / 128, N_TOK / 128, 16), blk, 0, stream>>>(xcb, Wt2, P, N_TOK, N_XP, D_INNER, 128);
  // 4) reduce -> bcP (packed bf16 [tok][n]) + dtr
  reduce_bc<<<N_TOK / 4, blk, 0, stream>>>(P, bcP, dtr);
  // 5) pack streams
  pack_kernel<<<dim3(N_TOK / 32, D_INNER / 64), blk, 0, stream>>>(xzf, xc, dtr, dt_w, dt_b, Dvec, uaT, ug2);
  // 6) chunked scan: partial -> combine -> final
  scan_partial<<<4096, blk, 0, stream>>>(uaT, bcP, A_log, Pp, sloc);
  scan_combine<<<1024, blk, 0, stream>>>(Pp, sloc, sin, state_out);
  scan_final<<<4096, blk, 0, stream>>>(uaT, bcP, A_log, sin, praw);
  // 7) gate (transpose praw [d][tok] -> ybb [tok][d])
  gate_kernel<<<dim3(N_TOK / 64, D_INNER / 64), blk, 0, stream>>>(praw, ug2, ybb);
  // 8) out = y @ out_proj_w : split-K x4 (kchunk=512) + reduce
  gemm_splitk<<<dim3(D_MODEL / 128, N_TOK / 128, 4), blk, 0, stream>>>(ybb, Wt3, Pg, N_TOK, D_MODEL, D_INNER, 512);
  reduce_z<4><<<(N_TOK * D_MODEL) / 1024, blk, 0, stream>>>(Pg, out, N_TOK * D_MODEL);
}

// Round 7
// 318.136 us; speedup vs baseline: 1.2154x; 1.0322x over previous
//
#include <hip/hip_runtime.h>
#include <hip/hip_bf16.h>

// Mamba block on MI355X. B=2, L=512, d_model=1024, d_inner=2048, d_state=64, K=4.
// Pipeline:
//   transpose x3 : weights -> bf16 [N][K]
//   gemm1 : xzf[1024][4096] = x @ Wt1^T   (MFMA bf16, BM=64 tile, 512 blocks)
//   conv  : xc = silu(causal depthwise conv(xs)) f32 + bf16 copy
//   gemm2 : split-K x16 partials of xcb @ Wt2^T -> P  (BM=64)
//   reduce_bc : P -> bc8[tok/8][n][8] (packed bf16 {B,C}) + dtr[tok]
//   pack  : uaT[d][tok]={dt,dt*x} f32x2 ; ug2[tok][d]=bf16x2{D*x,g}
//   scan_fused : block per (b,d), 4 waves = 4 chunks x 128 toks.
//                phase1 partial (P=prod dA, s_loc) -> LDS combine -> phase2
//                full recurrence + DPP reduce -> praw[d][tok]; state_out.
//   gate  : LDS-transpose, ybb[tok][d] = bf16((praw + D*x) * g)
//   gemm3 : split-K x4 partials of ybb @ Wt3^T (BM=64) ; reduce_z -> out

#define N_TOK   1024
#define SEQ_L   512
#define D_MODEL 1024
#define D_INNER 2048
#define D_STATE 64
#define D_XZ    4096
#define N_XP    129

typedef __attribute__((ext_vector_type(8))) short bf16x8;
typedef __attribute__((ext_vector_type(4))) float f32x4;

__device__ __forceinline__ unsigned short f2bf(float f) {
  __hip_bfloat16 h = __float2bfloat16(f);
  return *reinterpret_cast<unsigned short*>(&h);
}
__device__ __forceinline__ float bf16lo(unsigned int u) { return __uint_as_float(u << 16); }
__device__ __forceinline__ float bf16hi(unsigned int u) { return __uint_as_float(u & 0xffff0000u); }

// ---------- transpose + f32->bf16 convert: dst[C][R] = bf16(src[R][C]) ----------
__global__ __launch_bounds__(256) void transpose_bf16(
    const float* __restrict__ src, __hip_bfloat16* __restrict__ dst, int R, int C) {
  __shared__ float t[64][65];
  int c0 = blockIdx.x * 64, r0 = blockIdx.y * 64;
  int tc = threadIdx.x & 63, tg = threadIdx.x >> 6;
#pragma unroll
  for (int i = 0; i < 16; ++i) {
    int r = r0 + tg + i * 4, c = c0 + tc;
    t[tg + i * 4][tc] = (r < R && c < C) ? src[(size_t)r * C + c] : 0.f;
  }
  __syncthreads();
#pragma unroll
  for (int i = 0; i < 16; ++i) {
    int c = c0 + tg + i * 4, r = r0 + tc;
    if (c < C && r < R) dst[(size_t)c * R + r] = __float2bfloat16(t[tc][tg + i * 4]);
  }
}

// ---------- MFMA bf16 TN GEMM (full-K): C[M][N] = A[M][K] @ Bt[N][K]^T ----------
// BM x 128 tile, BK=32, 4 waves (2x2); wave tile (BM/2) x 64.
template<int BM, int A_F32>
__global__ __launch_bounds__(256) void gemm_bf16_tn(
    const void* __restrict__ Av, const __hip_bfloat16* __restrict__ Bt,
    float* __restrict__ C, int M, int N, int K) {
  const int MF = BM / 32;
  __shared__ short As[BM][40];   // rows padded to 80 B
  __shared__ short Bs[128][40];
  const int brow = blockIdx.y * BM, bcol = blockIdx.x * 128;
  const int tid = threadIdx.x;
  const int lane = tid & 63, wave = tid >> 6;
  const int wm = wave >> 1, wn = wave & 1;
  const int l15 = lane & 15, lk = lane >> 4;
  f32x4 acc[MF][4] = {};
  for (int k0 = 0; k0 < K; k0 += 32) {
#pragma unroll
    for (int i = 0; i < BM / 64; ++i) {
      int v = tid + i * 256;
      int r = v >> 2, kc = (v & 3) * 8;
      if (A_F32) {
        const float* Af = (const float*)Av;
        float4 f0 = *(const float4*)&Af[(size_t)(brow + r) * K + k0 + kc];
        float4 f1 = *(const float4*)&Af[(size_t)(brow + r) * K + k0 + kc + 4];
        bf16x8 h;
        h[0] = (short)f2bf(f0.x); h[1] = (short)f2bf(f0.y);
        h[2] = (short)f2bf(f0.z); h[3] = (short)f2bf(f0.w);
        h[4] = (short)f2bf(f1.x); h[5] = (short)f2bf(f1.y);
        h[6] = (short)f2bf(f1.z); h[7] = (short)f2bf(f1.w);
        *(bf16x8*)((char*)&As[0][0] + r * 80 + kc * 2) = h;
      } else {
        const __hip_bfloat16* Ab = (const __hip_bfloat16*)Av;
        *(bf16x8*)((char*)&As[0][0] + r * 80 + kc * 2) =
            *(const bf16x8*)&Ab[(size_t)(brow + r) * K + k0 + kc];
      }
    }
#pragma unroll
    for (int i = 0; i < 2; ++i) {
      int v = tid + i * 256;
      int r = v >> 2, kc = (v & 3) * 8;
      *(bf16x8*)((char*)&Bs[0][0] + r * 80 + kc * 2) =
          *(const bf16x8*)&Bt[(size_t)(bcol + r) * K + k0 + kc];
    }
    __syncthreads();
    bf16x8 af[MF], bfr[4];
#pragma unroll
    for (int m = 0; m < MF; ++m)
      af[m] = *(const bf16x8*)((const char*)&As[0][0] + (wm * (BM / 2) + m * 16 + l15) * 80 + lk * 16);
#pragma unroll
    for (int n = 0; n < 4; ++n)
      bfr[n] = *(const bf16x8*)((const char*)&Bs[0][0] + (wn * 64 + n * 16 + l15) * 80 + lk * 16);
#pragma unroll
    for (int m = 0; m < MF; ++m)
#pragma unroll
      for (int n = 0; n < 4; ++n)
        acc[m][n] = __builtin_amdgcn_mfma_f32_16x16x32_bf16(af[m], bfr[n], acc[m][n], 0, 0, 0);
    __syncthreads();
  }
#pragma unroll
  for (int m = 0; m < MF; ++m) {
    int row = brow + wm * (BM / 2) + m * 16 + lk * 4;
#pragma unroll
    for (int n = 0; n < 4; ++n) {
      int col = bcol + wn * 64 + n * 16 + l15;
#pragma unroll
      for (int r = 0; r < 4; ++r)
        C[(size_t)(row + r) * N + col] = acc[m][n][r];
    }
  }
}

// ---------- split-K MFMA GEMM: P[z][M][N] partials ----------
template<int BM>
__global__ __launch_bounds__(256) void gemm_splitk(
    const __hip_bfloat16* __restrict__ A, const __hip_bfloat16* __restrict__ Bt,
    float* __restrict__ P, int M, int N, int K, int kchunk) {
  const int MF = BM / 32;
  __shared__ short As[BM][40];
  __shared__ short Bs[128][40];
  const int brow = blockIdx.y * BM, bcol = blockIdx.x * 128;
  const int kbase = blockIdx.z * kchunk;
  const int tid = threadIdx.x;
  const int lane = tid & 63, wave = tid >> 6;
  const int wm = wave >> 1, wn = wave & 1;
  const int l15 = lane & 15, lk = lane >> 4;
  f32x4 acc[MF][4] = {};
  for (int k0 = kbase; k0 < kbase + kchunk; k0 += 32) {
#pragma unroll
    for (int i = 0; i < BM / 64; ++i) {
      int v = tid + i * 256;
      int r = v >> 2, kc = (v & 3) * 8;
      *(bf16x8*)((char*)&As[0][0] + r * 80 + kc * 2) =
          *(const bf16x8*)&A[(size_t)(brow + r) * K + k0 + kc];
    }
#pragma unroll
    for (int i = 0; i < 2; ++i) {
      int v = tid + i * 256;
      int r = v >> 2, kc = (v & 3) * 8;
      bf16x8 bv = {};
      if ((bcol + r) < N)
        bv = *(const bf16x8*)&Bt[(size_t)(bcol + r) * K + k0 + kc];
      *(bf16x8*)((char*)&Bs[0][0] + r * 80 + kc * 2) = bv;
    }
    __syncthreads();
    bf16x8 af[MF], bfr[4];
#pragma unroll
    for (int m = 0; m < MF; ++m)
      af[m] = *(const bf16x8*)((const char*)&As[0][0] + (wm * (BM / 2) + m * 16 + l15) * 80 + lk * 16);
#pragma unroll
    for (int n = 0; n < 4; ++n)
      bfr[n] = *(const bf16x8*)((const char*)&Bs[0][0] + (wn * 64 + n * 16 + l15) * 80 + lk * 16);
#pragma unroll
    for (int m = 0; m < MF; ++m)
#pragma unroll
      for (int n = 0; n < 4; ++n)
        acc[m][n] = __builtin_amdgcn_mfma_f32_16x16x32_bf16(af[m], bfr[n], acc[m][n], 0, 0, 0);
    __syncthreads();
  }
  float* Pz = P + (size_t)blockIdx.z * M * N;
#pragma unroll
  for (int m = 0; m < MF; ++m) {
    int row = brow + wm * (BM / 2) + m * 16 + lk * 4;
#pragma unroll
    for (int n = 0; n < 4; ++n) {
      int col = bcol + wn * 64 + n * 16 + l15;
      if (col < N) {
#pragma unroll
        for (int r = 0; r < 4; ++r)
          Pz[(size_t)(row + r) * N + col] = acc[m][n][r];
      }
    }
  }
}

// ---------- reduce Z partials elementwise (vectorized x4) ----------
template<int Z>
__global__ __launch_bounds__(256) void reduce_z(
    const float* __restrict__ P, float* __restrict__ out, int n) {
  int i = (blockIdx.x * 256 + threadIdx.x) * 4;
  if (i >= n) return;
  float4 s = *(const float4*)&P[i];
#pragma unroll
  for (int z = 1; z < Z; ++z) {
    float4 v = *(const float4*)&P[(size_t)z * n + i];
    s.x += v.x; s.y += v.y; s.z += v.z; s.w += v.w;
  }
  *(float4*)&out[i] = s;
}

// ---------- reduce partials -> bc8[tok/8][n][8] (packed bf16 {B,C}) + dtr ----------
__global__ __launch_bounds__(256) void reduce_bc(
    const float* __restrict__ P, unsigned int* __restrict__ bc8,
    float* __restrict__ dtr) {
  int tok = blockIdx.x * 4 + (threadIdx.x >> 6);
  int n = threadIdx.x & 63;
  const float* p0 = P + (size_t)tok * N_XP + n;
  float sB = 0.f, sC = 0.f;
#pragma unroll
  for (int z = 0; z < 16; ++z) {
    sB += p0[(size_t)z * N_TOK * N_XP];
    sC += p0[(size_t)z * N_TOK * N_XP + 64];
  }
  bc8[(size_t)(tok >> 3) * 512 + n * 8 + (tok & 7)] =
      (unsigned)f2bf(sB) | ((unsigned)f2bf(sC) << 16);
  if (n == 0) {
    float sd = 0.f;
    const float* pd = P + (size_t)tok * N_XP + 128;
#pragma unroll
    for (int z = 0; z < 16; ++z) sd += pd[(size_t)z * N_TOK * N_XP];
    dtr[tok] = sd;
  }
}

// ---------- causal depthwise conv (K=4) + SiLU ----------
__global__ __launch_bounds__(256) void conv_silu_kernel(
    const float* __restrict__ xz, const float* __restrict__ cw,
    const float* __restrict__ cb, float* __restrict__ xc,
    __hip_bfloat16* __restrict__ xcb) {
  int idx = blockIdx.x * 256 + threadIdx.x;
  int c = idx & (D_INNER - 1);
  int tok = idx >> 11;
  int l = tok & (SEQ_L - 1);
  float acc = cb[c];
#pragma unroll
  for (int k = 0; k < 4; ++k) {
    int ll = l - 3 + k;
    if (ll >= 0) acc = fmaf(xz[(size_t)(tok - 3 + k) * D_XZ + c], cw[c * 4 + k], acc);
  }
  float v = acc / (1.f + __expf(-acc));
  xc[idx] = v;
  xcb[idx] = __float2bfloat16(v);
}

// ---------- pack: uaT[d][tok]={dt,dt*x} (LDS transpose); ug2[tok][d]={Dx,g} ----------
__global__ __launch_bounds__(256) void pack_kernel(
    const float* __restrict__ xzf, const float* __restrict__ xc,
    const float* __restrict__ dtr, const float* __restrict__ dt_w,
    const float* __restrict__ dt_b, const float* __restrict__ Dv,
    float2* __restrict__ uaT, unsigned int* __restrict__ ug2) {
  __shared__ float2 la[64][33];
  int tok0 = blockIdx.x * 32, d0 = blockIdx.y * 64;
  int t = threadIdx.x;
  int dl = t & 63, tc = t >> 6;
  int d = d0 + dl;
  float w = dt_w[d], bb = dt_b[d], Dd = Dv[d];
#pragma unroll
  for (int p = 0; p < 8; ++p) {
    int tl = p * 4 + tc;
    int tok = tok0 + tl;
    float xt = xc[(size_t)tok * D_INNER + d];
    float z = xzf[(size_t)tok * D_XZ + D_INNER + d];
    float dt = dtr[tok] * w + bb;
    dt = (dt > 20.f) ? dt : log1pf(__expf(dt));
    la[dl][tl] = make_float2(dt, dt * xt);
    float g = z / (1.f + __expf(-z));
    ug2[(size_t)tok * D_INNER + d] =
        (unsigned int)f2bf(Dd * xt) | ((unsigned int)f2bf(g) << 16);
  }
  __syncthreads();
  int tl2 = t & 31, dg = t >> 5;
#pragma unroll
  for (int q = 0; q < 8; ++q) {
    int dl2 = q * 8 + dg;
    uaT[(size_t)(d0 + dl2) * N_TOK + tok0 + tl2] = la[dl2][tl2];
  }
}

// ---------- gate w/ LDS transpose: ybb[tok][d] = bf16((praw[d][tok] + Dx)*g) ----------
__global__ __launch_bounds__(256) void gate_kernel(
    const float* __restrict__ praw, const unsigned int* __restrict__ ug2,
    __hip_bfloat16* __restrict__ ybb) {
  __shared__ float tile[64][65];
  int tok0 = blockIdx.x * 64, d0 = blockIdx.y * 64;
  int t = threadIdx.x, tc = t & 63, tg = t >> 6;
#pragma unroll
  for (int i = 0; i < 16; ++i) {
    int dl = tg + i * 4;
    tile[dl][tc] = praw[(size_t)(d0 + dl) * N_TOK + tok0 + tc];
  }
  __syncthreads();
#pragma unroll
  for (int i = 0; i < 16; ++i) {
    int tl = tg + i * 4;
    size_t idx = (size_t)(tok0 + tl) * D_INNER + d0 + tc;
    unsigned u = ug2[idx];
    float v = (tile[tc][tl] + bf16lo(u)) * bf16hi(u);
    ybb[idx] = __float2bfloat16(v);
  }
}

// ---------- DPP wave-64 sum: result in lane 63 ----------
template<int CTRL>
__device__ __forceinline__ float dppadd(float v) {
  int t = __builtin_amdgcn_update_dpp(0, __float_as_int(v), CTRL, 0xF, 0xF, true);
  return v + __int_as_float(t);
}
__device__ __forceinline__ float wave_sum64(float v) {
  v = dppadd<0x111>(v);  // row_shr:1
  v = dppadd<0x112>(v);  // row_shr:2
  v = dppadd<0x114>(v);  // row_shr:4
  v = dppadd<0x118>(v);  // row_shr:8
  v = dppadd<0x142>(v);  // row_bcast:15
  v = dppadd<0x143>(v);  // row_bcast:31
  return v;
}

// ---------- fused chunked scan: block = (b,d), wave = chunk ----------
#define PTOK(dtv, dtxv, bu) { \
    float dA = __expf((dtv) * a); \
    Pr *= dA; \
    s = fmaf(dA, s, (dtxv) * bf16lo(bu)); }

#define FTOK(dtv, dtxv, bu, pj) { \
    float dA = __expf((dtv) * a); \
    s = fmaf(dA, s, (dtxv) * bf16lo(bu)); \
    pj = wave_sum64(s * bf16hi(bu)); }

__global__ __launch_bounds__(256) void scan_fused(
    const float2* __restrict__ uaT, const unsigned int* __restrict__ bc8,
    const float* __restrict__ A_log, float* __restrict__ praw,
    float* __restrict__ state_out) {
  __shared__ float lP[4][64], lS[4][64];
  int bd = blockIdx.x;                      // b*2048 + d
  int d = bd & (D_INNER - 1), b = bd >> 11;
  int ch = threadIdx.x >> 6, lane = threadIdx.x & 63;
  float a = -__expf(A_log[d * D_STATE + lane]);
  int tok0 = b * SEQ_L + ch * 128;
  const float4* uq0 = (const float4*)(uaT + (size_t)d * N_TOK + tok0);
  const uint4* bq0 = (const uint4*)bc8 + (size_t)(tok0 >> 3) * 128 + lane * 2;

  // ---- phase 1: local scan (decay product + local state), 2-deep prefetch ----
  float s = 0.f, Pr = 1.f;
  {
    const float4* uq = uq0; const uint4* bq = bq0;
    uint4 q0 = bq[0], q1 = bq[1];
    float4 u0 = uq[0], u1 = uq[1], u2 = uq[2], u3 = uq[3];
#pragma unroll 1
    for (int it = 0; it < 16; ++it) {
      bq += 128; uq += 4;
      uint4 nq0 = bq[0], nq1 = bq[1];           // prefetch (last iter over-reads
      float4 nu0 = uq[0], nu1 = uq[1];          //  <=2KB into next ws region: safe)
      float4 nu2 = uq[2], nu3 = uq[3];
      PTOK(u0.x, u0.y, q0.x) PTOK(u0.z, u0.w, q0.y)
      PTOK(u1.x, u1.y, q0.z) PTOK(u1.z, u1.w, q0.w)
      PTOK(u2.x, u2.y, q1.x) PTOK(u2.z, u2.w, q1.y)
      PTOK(u3.x, u3.y, q1.z) PTOK(u3.z, u3.w, q1.w)
      q0 = nq0; q1 = nq1; u0 = nu0; u1 = nu1; u2 = nu2; u3 = nu3;
    }
  }
  lP[ch][lane] = Pr; lS[ch][lane] = s;
  __syncthreads();
  // ---- combine: s_in for this chunk; wave 3 also emits final state ----
  float sin = 0.f;
#pragma unroll
  for (int c = 0; c < 3; ++c)
    if (c < ch) sin = fmaf(lP[c][lane], sin, lS[c][lane]);
  if (ch == 3)
    state_out[(size_t)bd * D_STATE + lane] = fmaf(lP[3][lane], sin, lS[3][lane]);

  // ---- phase 2: full recurrence + DPP reduce ----
  s = sin;
  {
    const float4* uq = uq0; const uint4* bq = bq0;
    float* po = praw + (size_t)d * N_TOK + tok0;
    uint4 q0 = bq[0], q1 = bq[1];
    float4 u0 = uq[0], u1 = uq[1], u2 = uq[2], u3 = uq[3];
#pragma unroll 1
    for (int it = 0; it < 16; ++it) {
      bq += 128; uq += 4;
      uint4 nq0 = bq[0], nq1 = bq[1];
      float4 nu0 = uq[0], nu1 = uq[1];
      float4 nu2 = uq[2], nu3 = uq[3];
      float p0, p1, p2, p3, p4, p5, p6, p7;
      FTOK(u0.x, u0.y, q0.x, p0) FTOK(u0.z, u0.w, q0.y, p1)
      FTOK(u1.x, u1.y, q0.z, p2) FTOK(u1.z, u1.w, q0.w, p3)
      FTOK(u2.x, u2.y, q1.x, p4) FTOK(u2.z, u2.w, q1.y, p5)
      FTOK(u3.x, u3.y, q1.z, p6) FTOK(u3.z, u3.w, q1.w, p7)
      if (lane == 63) {
        *(float4*)(po) = make_float4(p0, p1, p2, p3);
        *(float4*)(po + 4) = make_float4(p4, p5, p6, p7);
      }
      po += 8;
      q0 = nq0; q1 = nq1; u0 = nu0; u1 = nu1; u2 = nu2; u3 = nu3;
    }
  }
}

extern "C" void kernel_launch(void* const* d_in, const int* in_sizes, int n_in,
                              void* d_out, int out_size, void* d_ws, size_t ws_size,
                              hipStream_t stream) {
  const float* x         = (const float*)d_in[0];
  const float* in_proj_w = (const float*)d_in[1];
  const float* conv_w    = (const float*)d_in[2];
  const float* conv_b    = (const float*)d_in[3];
  const float* x_proj_w  = (const float*)d_in[4];
  const float* dt_w      = (const float*)d_in[5];
  const float* dt_b      = (const float*)d_in[6];
  const float* A_log     = (const float*)d_in[7];
  const float* Dvec      = (const float*)d_in[8];
  const float* out_proj_w= (const float*)d_in[9];

  char* w = (char*)d_ws;
  __hip_bfloat16* Wt1 = (__hip_bfloat16*)w; w += (size_t)D_XZ * D_MODEL * 2;      // 8 MB
  __hip_bfloat16* Wt2 = (__hip_bfloat16*)w; w += (size_t)N_XP * D_INNER * 2;      // 516 KB
  __hip_bfloat16* Wt3 = (__hip_bfloat16*)w; w += (size_t)D_MODEL * D_INNER * 2;   // 4 MB
  float*          xzf = (float*)w;          w += (size_t)N_TOK * D_XZ * 4;        // 16 MB
  float*          xc  = (float*)w;          w += (size_t)N_TOK * D_INNER * 4;     // 8 MB
  __hip_bfloat16* xcb = (__hip_bfloat16*)w; w += (size_t)N_TOK * D_INNER * 2;     // 4 MB
  float*          P   = (float*)w;          w += (size_t)16 * N_TOK * N_XP * 4;   // 8.45 MB
  unsigned int*   bc8 = (unsigned int*)w;   w += (size_t)N_TOK * D_STATE * 4;     // 256 KB
  float*          dtr = (float*)w;          w += (size_t)N_TOK * 4;               // 4 KB
  float2*         uaT = (float2*)w;         w += (size_t)D_INNER * N_TOK * 8;     // 16 MB
  unsigned int*   ug2 = (unsigned int*)w;   w += (size_t)N_TOK * D_INNER * 4;     // 8 MB
  // aliases (lifetimes):
  float*          praw = P;            // 8 MB <= 8.45 MB; P dead after reduce_bc
  __hip_bfloat16* ybb  = xcb;          // 4 MB; xcb dead after gemm2
  float*          Pg   = xzf;          // 16 MB; xzf dead after pack

  float* out       = (float*)d_out;
  float* state_out = out + (size_t)N_TOK * D_MODEL;

  dim3 blk(256);
  transpose_bf16<<<dim3(D_XZ / 64, D_MODEL / 64), blk, 0, stream>>>(in_proj_w, Wt1, D_MODEL, D_XZ);
  transpose_bf16<<<dim3((N_XP + 63) / 64, D_INNER / 64), blk, 0, stream>>>(x_proj_w, Wt2, D_INNER, N_XP);
  transpose_bf16<<<dim3(D_MODEL / 64, D_INNER / 64), blk, 0, stream>>>(out_proj_w, Wt3, D_INNER, D_MODEL);
  // 1) xz = x @ in_proj_w  (BM=64: 32x16 = 512 blocks)
  gemm_bf16_tn<64, 1><<<dim3(D_XZ / 128, N_TOK / 64), blk, 0, stream>>>(x, Wt1, xzf, N_TOK, D_XZ, D_MODEL);
  // 2) conv + silu
  conv_silu_kernel<<<(N_TOK * D_INNER) / 256, blk, 0, stream>>>(xzf, conv_w, conv_b, xc, xcb);
  // 3) xp partials: split-K x16 (BM=64: 2x16x16 = 512 blocks)
  gemm_splitk<64><<<dim3((N_XP + 127) / 128, N_TOK / 64, 16), blk, 0, stream>>>(xcb, Wt2, P, N_TOK, N_XP, D_INNER, 128);
  // 4) reduce -> bc8 + dtr
  reduce_bc<<<N_TOK / 4, blk, 0, stream>>>(P, bc8, dtr);
  // 5) pack streams
  pack_kernel<<<dim3(N_TOK / 32, D_INNER / 64), blk, 0, stream>>>(xzf, xc, dtr, dt_w, dt_b, Dvec, uaT, ug2);
  // 6) fused chunked scan
  scan_fused<<<2 * D_INNER, blk, 0, stream>>>(uaT, bc8, A_log, praw, state_out);
  // 7) gate (transpose praw [d][tok] -> ybb [tok][d])
  gate_kernel<<<dim3(N_TOK / 64, D_INNER / 64), blk, 0, stream>>>(praw, ug2, ybb);
  // 8) out = y @ out_proj_w : split-K x4 (BM=64: 8x16x4 = 512 blocks) + reduce
  gemm_splitk<64><<<dim3(D_MODEL / 128, N_TOK / 64, 4), blk, 0, stream>>>(ybb, Wt3, Pg, N_TOK, D_MODEL, D_INNER, 512);
  reduce_z<4><<<(N_TOK * D_MODEL) / 1024, blk, 0, stream>>>(Pg, out, N_TOK * D_MODEL);
}

// Round 9
// 314.267 us; speedup vs baseline: 1.2304x; 1.0123x over previous
//
#include <hip/hip_runtime.h>
#include <hip/hip_bf16.h>

// Mamba block on MI355X. B=2, L=512, d_model=1024, d_inner=2048, d_state=64, K=4.
// Pipeline:
//   transpose x3 : weights -> bf16 [N][K]; convert x -> bf16
//   gemm1 : xzf[1024][4096] = xb @ Wt1^T   (MFMA bf16, BM=64 tile, 512 blocks)
//   conv  : xc = silu(causal depthwise conv(xs)) f32 + bf16 copy
//   gemm2 : split-K x16 partials of xcb @ Wt2^T -> P  (BM=64)
//   reduce_bc : P -> bc8[tok/8][n][8] (packed bf16 {B,C}) + dtr[tok]
//   pack  : uaT[d][tok]={dt,dt*x} f32x2 ; ug2[tok][d]=bf16x2{D*x,g}
//   scan_fused : block per (b,d), 4 waves = 4 chunks x 128 toks.
//                phase1 partial (P=prod dA, s_loc) -> LDS combine -> phase2
//                full recurrence + DPP reduce (builtin update_dpp; GCNDPPCombine
//                folds to v_add_f32_dpp with compiler-managed hazards).
//                exp via exp2f with prescaled a2 = -exp(A_log)*log2(e).
//   gate  : LDS-transpose, ybb[tok][d] = bf16((praw + D*x) * g)
//   gemm3 : split-K x4 partials of ybb @ Wt3^T (BM=64) ; reduce_z -> out

#define N_TOK   1024
#define SEQ_L   512
#define D_MODEL 1024
#define D_INNER 2048
#define D_STATE 64
#define D_XZ    4096
#define N_XP    129

typedef __attribute__((ext_vector_type(8))) short bf16x8;
typedef __attribute__((ext_vector_type(4))) float f32x4;

__device__ __forceinline__ unsigned short f2bf(float f) {
  __hip_bfloat16 h = __float2bfloat16(f);
  return *reinterpret_cast<unsigned short*>(&h);
}
__device__ __forceinline__ float bf16lo(unsigned int u) { return __uint_as_float(u << 16); }
__device__ __forceinline__ float bf16hi(unsigned int u) { return __uint_as_float(u & 0xffff0000u); }

// ---------- transpose + f32->bf16 convert: dst[C][R] = bf16(src[R][C]) ----------
__global__ __launch_bounds__(256) void transpose_bf16(
    const float* __restrict__ src, __hip_bfloat16* __restrict__ dst, int R, int C) {
  __shared__ float t[64][65];
  int c0 = blockIdx.x * 64, r0 = blockIdx.y * 64;
  int tc = threadIdx.x & 63, tg = threadIdx.x >> 6;
#pragma unroll
  for (int i = 0; i < 16; ++i) {
    int r = r0 + tg + i * 4, c = c0 + tc;
    t[tg + i * 4][tc] = (r < R && c < C) ? src[(size_t)r * C + c] : 0.f;
  }
  __syncthreads();
#pragma unroll
  for (int i = 0; i < 16; ++i) {
    int c = c0 + tg + i * 4, r = r0 + tc;
    if (c < C && r < R) dst[(size_t)c * R + r] = __float2bfloat16(t[tc][tg + i * 4]);
  }
}

__global__ __launch_bounds__(256) void convert_bf16(
    const float* __restrict__ src, __hip_bfloat16* __restrict__ dst, int n) {
  int i = blockIdx.x * 256 + threadIdx.x;
  if (i < n) dst[i] = __float2bfloat16(src[i]);
}

// ---------- MFMA bf16 TN GEMM (full-K): C[M][N] = A[M][K] @ Bt[N][K]^T ----------
template<int BM>
__global__ __launch_bounds__(256) void gemm_bf16_tn(
    const __hip_bfloat16* __restrict__ A, const __hip_bfloat16* __restrict__ Bt,
    float* __restrict__ C, int M, int N, int K) {
  const int MF = BM / 32;
  __shared__ short As[BM][40];   // rows padded to 80 B
  __shared__ short Bs[128][40];
  const int brow = blockIdx.y * BM, bcol = blockIdx.x * 128;
  const int tid = threadIdx.x;
  const int lane = tid & 63, wave = tid >> 6;
  const int wm = wave >> 1, wn = wave & 1;
  const int l15 = lane & 15, lk = lane >> 4;
  f32x4 acc[MF][4] = {};
  for (int k0 = 0; k0 < K; k0 += 32) {
#pragma unroll
    for (int i = 0; i < BM / 64; ++i) {
      int v = tid + i * 256;
      int r = v >> 2, kc = (v & 3) * 8;
      *(bf16x8*)((char*)&As[0][0] + r * 80 + kc * 2) =
          *(const bf16x8*)&A[(size_t)(brow + r) * K + k0 + kc];
    }
#pragma unroll
    for (int i = 0; i < 2; ++i) {
      int v = tid + i * 256;
      int r = v >> 2, kc = (v & 3) * 8;
      *(bf16x8*)((char*)&Bs[0][0] + r * 80 + kc * 2) =
          *(const bf16x8*)&Bt[(size_t)(bcol + r) * K + k0 + kc];
    }
    __syncthreads();
    bf16x8 af[MF], bfr[4];
#pragma unroll
    for (int m = 0; m < MF; ++m)
      af[m] = *(const bf16x8*)((const char*)&As[0][0] + (wm * (BM / 2) + m * 16 + l15) * 80 + lk * 16);
#pragma unroll
    for (int n = 0; n < 4; ++n)
      bfr[n] = *(const bf16x8*)((const char*)&Bs[0][0] + (wn * 64 + n * 16 + l15) * 80 + lk * 16);
#pragma unroll
    for (int m = 0; m < MF; ++m)
#pragma unroll
      for (int n = 0; n < 4; ++n)
        acc[m][n] = __builtin_amdgcn_mfma_f32_16x16x32_bf16(af[m], bfr[n], acc[m][n], 0, 0, 0);
    __syncthreads();
  }
#pragma unroll
  for (int m = 0; m < MF; ++m) {
    int row = brow + wm * (BM / 2) + m * 16 + lk * 4;
#pragma unroll
    for (int n = 0; n < 4; ++n) {
      int col = bcol + wn * 64 + n * 16 + l15;
#pragma unroll
      for (int r = 0; r < 4; ++r)
        C[(size_t)(row + r) * N + col] = acc[m][n][r];
    }
  }
}

// ---------- split-K MFMA GEMM: P[z][M][N] partials ----------
template<int BM>
__global__ __launch_bounds__(256) void gemm_splitk(
    const __hip_bfloat16* __restrict__ A, const __hip_bfloat16* __restrict__ Bt,
    float* __restrict__ P, int M, int N, int K, int kchunk) {
  const int MF = BM / 32;
  __shared__ short As[BM][40];
  __shared__ short Bs[128][40];
  const int brow = blockIdx.y * BM, bcol = blockIdx.x * 128;
  const int kbase = blockIdx.z * kchunk;
  const int tid = threadIdx.x;
  const int lane = tid & 63, wave = tid >> 6;
  const int wm = wave >> 1, wn = wave & 1;
  const int l15 = lane & 15, lk = lane >> 4;
  f32x4 acc[MF][4] = {};
  for (int k0 = kbase; k0 < kbase + kchunk; k0 += 32) {
#pragma unroll
    for (int i = 0; i < BM / 64; ++i) {
      int v = tid + i * 256;
      int r = v >> 2, kc = (v & 3) * 8;
      *(bf16x8*)((char*)&As[0][0] + r * 80 + kc * 2) =
          *(const bf16x8*)&A[(size_t)(brow + r) * K + k0 + kc];
    }
#pragma unroll
    for (int i = 0; i < 2; ++i) {
      int v = tid + i * 256;
      int r = v >> 2, kc = (v & 3) * 8;
      bf16x8 bv = {};
      if ((bcol + r) < N)
        bv = *(const bf16x8*)&Bt[(size_t)(bcol + r) * K + k0 + kc];
      *(bf16x8*)((char*)&Bs[0][0] + r * 80 + kc * 2) = bv;
    }
    __syncthreads();
    bf16x8 af[MF], bfr[4];
#pragma unroll
    for (int m = 0; m < MF; ++m)
      af[m] = *(const bf16x8*)((const char*)&As[0][0] + (wm * (BM / 2) + m * 16 + l15) * 80 + lk * 16);
#pragma unroll
    for (int n = 0; n < 4; ++n)
      bfr[n] = *(const bf16x8*)((const char*)&Bs[0][0] + (wn * 64 + n * 16 + l15) * 80 + lk * 16);
#pragma unroll
    for (int m = 0; m < MF; ++m)
#pragma unroll
      for (int n = 0; n < 4; ++n)
        acc[m][n] = __builtin_amdgcn_mfma_f32_16x16x32_bf16(af[m], bfr[n], acc[m][n], 0, 0, 0);
    __syncthreads();
  }
  float* Pz = P + (size_t)blockIdx.z * M * N;
#pragma unroll
  for (int m = 0; m < MF; ++m) {
    int row = brow + wm * (BM / 2) + m * 16 + lk * 4;
#pragma unroll
    for (int n = 0; n < 4; ++n) {
      int col = bcol + wn * 64 + n * 16 + l15;
      if (col < N) {
#pragma unroll
        for (int r = 0; r < 4; ++r)
          Pz[(size_t)(row + r) * N + col] = acc[m][n][r];
      }
    }
  }
}

// ---------- reduce Z partials elementwise (vectorized x4) ----------
template<int Z>
__global__ __launch_bounds__(256) void reduce_z(
    const float* __restrict__ P, float* __restrict__ out, int n) {
  int i = (blockIdx.x * 256 + threadIdx.x) * 4;
  if (i >= n) return;
  float4 s = *(const float4*)&P[i];
#pragma unroll
  for (int z = 1; z < Z; ++z) {
    float4 v = *(const float4*)&P[(size_t)z * n + i];
    s.x += v.x; s.y += v.y; s.z += v.z; s.w += v.w;
  }
  *(float4*)&out[i] = s;
}

// ---------- reduce partials -> bc8[tok/8][n][8] (packed bf16 {B,C}) + dtr ----------
__global__ __launch_bounds__(256) void reduce_bc(
    const float* __restrict__ P, unsigned int* __restrict__ bc8,
    float* __restrict__ dtr) {
  int tok = blockIdx.x * 4 + (threadIdx.x >> 6);
  int n = threadIdx.x & 63;
  const float* p0 = P + (size_t)tok * N_XP + n;
  float sB = 0.f, sC = 0.f;
#pragma unroll
  for (int z = 0; z < 16; ++z) {
    sB += p0[(size_t)z * N_TOK * N_XP];
    sC += p0[(size_t)z * N_TOK * N_XP + 64];
  }
  bc8[(size_t)(tok >> 3) * 512 + n * 8 + (tok & 7)] =
      (unsigned)f2bf(sB) | ((unsigned)f2bf(sC) << 16);
  if (n == 0) {
    float sd = 0.f;
    const float* pd = P + (size_t)tok * N_XP + 128;
#pragma unroll
    for (int z = 0; z < 16; ++z) sd += pd[(size_t)z * N_TOK * N_XP];
    dtr[tok] = sd;
  }
}

// ---------- causal depthwise conv (K=4) + SiLU ----------
__global__ __launch_bounds__(256) void conv_silu_kernel(
    const float* __restrict__ xz, const float* __restrict__ cw,
    const float* __restrict__ cb, float* __restrict__ xc,
    __hip_bfloat16* __restrict__ xcb) {
  int idx = blockIdx.x * 256 + threadIdx.x;
  int c = idx & (D_INNER - 1);
  int tok = idx >> 11;
  int l = tok & (SEQ_L - 1);
  float acc = cb[c];
#pragma unroll
  for (int k = 0; k < 4; ++k) {
    int ll = l - 3 + k;
    if (ll >= 0) acc = fmaf(xz[(size_t)(tok - 3 + k) * D_XZ + c], cw[c * 4 + k], acc);
  }
  float v = acc / (1.f + __expf(-acc));
  xc[idx] = v;
  xcb[idx] = __float2bfloat16(v);
}

// ---------- pack: uaT[d][tok]={dt,dt*x} (LDS transpose); ug2[tok][d]={Dx,g} ----------
__global__ __launch_bounds__(256) void pack_kernel(
    const float* __restrict__ xzf, const float* __restrict__ xc,
    const float* __restrict__ dtr, const float* __restrict__ dt_w,
    const float* __restrict__ dt_b, const float* __restrict__ Dv,
    float2* __restrict__ uaT, unsigned int* __restrict__ ug2) {
  __shared__ float2 la[64][33];
  int tok0 = blockIdx.x * 32, d0 = blockIdx.y * 64;
  int t = threadIdx.x;
  int dl = t & 63, tc = t >> 6;
  int d = d0 + dl;
  float w = dt_w[d], bb = dt_b[d], Dd = Dv[d];
#pragma unroll
  for (int p = 0; p < 8; ++p) {
    int tl = p * 4 + tc;
    int tok = tok0 + tl;
    float xt = xc[(size_t)tok * D_INNER + d];
    float z = xzf[(size_t)tok * D_XZ + D_INNER + d];
    float dt = dtr[tok] * w + bb;
    dt = (dt > 20.f) ? dt : log1pf(__expf(dt));
    la[dl][tl] = make_float2(dt, dt * xt);
    float g = z / (1.f + __expf(-z));
    ug2[(size_t)tok * D_INNER + d] =
        (unsigned int)f2bf(Dd * xt) | ((unsigned int)f2bf(g) << 16);
  }
  __syncthreads();
  int tl2 = t & 31, dg = t >> 5;
#pragma unroll
  for (int q = 0; q < 8; ++q) {
    int dl2 = q * 8 + dg;
    uaT[(size_t)(d0 + dl2) * N_TOK + tok0 + tl2] = la[dl2][tl2];
  }
}

// ---------- gate w/ LDS transpose: ybb[tok][d] = bf16((praw[d][tok] + Dx)*g) ----------
__global__ __launch_bounds__(256) void gate_kernel(
    const float* __restrict__ praw, const unsigned int* __restrict__ ug2,
    __hip_bfloat16* __restrict__ ybb) {
  __shared__ float tile[64][65];
  int tok0 = blockIdx.x * 64, d0 = blockIdx.y * 64;
  int t = threadIdx.x, tc = t & 63, tg = t >> 6;
#pragma unroll
  for (int i = 0; i < 16; ++i) {
    int dl = tg + i * 4;
    tile[dl][tc] = praw[(size_t)(d0 + dl) * N_TOK + tok0 + tc];
  }
  __syncthreads();
#pragma unroll
  for (int i = 0; i < 16; ++i) {
    int tl = tg + i * 4;
    size_t idx = (size_t)(tok0 + tl) * D_INNER + d0 + tc;
    unsigned u = ug2[idx];
    float v = (tile[tc][tl] + bf16lo(u)) * bf16hi(u);
    ybb[idx] = __float2bfloat16(v);
  }
}

// ---------- DPP wave-64 sum (builtin; GCNDPPCombine folds to v_add_f32_dpp,
// compiler manages hazards). Result valid in lane 63. ----------
template<int CTRL>
__device__ __forceinline__ float dppadd(float v) {
  int t = __builtin_amdgcn_update_dpp(0, __float_as_int(v), CTRL, 0xF, 0xF, true);
  return v + __int_as_float(t);
}
__device__ __forceinline__ float wave_sum64(float v) {
  v = dppadd<0x111>(v);  // row_shr:1
  v = dppadd<0x112>(v);  // row_shr:2
  v = dppadd<0x114>(v);  // row_shr:4
  v = dppadd<0x118>(v);  // row_shr:8
  v = dppadd<0x142>(v);  // row_bcast:15
  v = dppadd<0x143>(v);  // row_bcast:31
  return v;
}

// ---------- fused chunked scan: block = (b,d), wave = chunk ----------
// a2 = -exp(A_log) * log2(e); dA = exp2(dt * a2)  (1 mul + 1 v_exp)
#define PTOK(dtv, dtxv, bu) { \
    float dA = exp2f((dtv) * a2); \
    Pr *= dA; \
    s = fmaf(dA, s, (dtxv) * bf16lo(bu)); }

#define FTOK(dtv, dtxv, bu, pj) { \
    float dA = exp2f((dtv) * a2); \
    s = fmaf(dA, s, (dtxv) * bf16lo(bu)); \
    pj = wave_sum64(s * bf16hi(bu)); }

__global__ __launch_bounds__(256) void scan_fused(
    const float2* __restrict__ uaT, const unsigned int* __restrict__ bc8,
    const float* __restrict__ A_log, float* __restrict__ praw,
    float* __restrict__ state_out) {
  __shared__ float lP[4][64], lS[4][64];
  int bd = blockIdx.x;                      // b*2048 + d
  int d = bd & (D_INNER - 1), b = bd >> 11;
  int ch = threadIdx.x >> 6, lane = threadIdx.x & 63;
  float a2 = -__expf(A_log[d * D_STATE + lane]) * 1.4426950408889634f;
  int tok0 = b * SEQ_L + ch * 128;
  const float4* uq = (const float4*)(uaT + (size_t)d * N_TOK + tok0);
  const uint4* bq = (const uint4*)bc8 + (size_t)(tok0 >> 3) * 128 + lane * 2;

  // ---- phase 1: local scan (decay product + local state) ----
  float s = 0.f, Pr = 1.f;
#pragma unroll 2
  for (int it = 0; it < 16; ++it) {
    uint4 q0 = bq[it * 128], q1 = bq[it * 128 + 1];
    float4 u0 = uq[it * 4], u1 = uq[it * 4 + 1];
    float4 u2 = uq[it * 4 + 2], u3 = uq[it * 4 + 3];
    PTOK(u0.x, u0.y, q0.x) PTOK(u0.z, u0.w, q0.y)
    PTOK(u1.x, u1.y, q0.z) PTOK(u1.z, u1.w, q0.w)
    PTOK(u2.x, u2.y, q1.x) PTOK(u2.z, u2.w, q1.y)
    PTOK(u3.x, u3.y, q1.z) PTOK(u3.z, u3.w, q1.w)
  }
  lP[ch][lane] = Pr; lS[ch][lane] = s;
  __syncthreads();
  // ---- combine: s_in for this chunk; wave 3 also emits final state ----
  float sin = 0.f;
#pragma unroll
  for (int c = 0; c < 3; ++c)
    if (c < ch) sin = fmaf(lP[c][lane], sin, lS[c][lane]);
  if (ch == 3)
    state_out[(size_t)bd * D_STATE + lane] = fmaf(lP[3][lane], sin, lS[3][lane]);

  // ---- phase 2: full recurrence + DPP reduce ----
  s = sin;
  float* po = praw + (size_t)d * N_TOK + tok0;
#pragma unroll 2
  for (int it = 0; it < 16; ++it) {
    uint4 q0 = bq[it * 128], q1 = bq[it * 128 + 1];
    float4 u0 = uq[it * 4], u1 = uq[it * 4 + 1];
    float4 u2 = uq[it * 4 + 2], u3 = uq[it * 4 + 3];
    float p0, p1, p2, p3, p4, p5, p6, p7;
    FTOK(u0.x, u0.y, q0.x, p0) FTOK(u0.z, u0.w, q0.y, p1)
    FTOK(u1.x, u1.y, q0.z, p2) FTOK(u1.z, u1.w, q0.w, p3)
    FTOK(u2.x, u2.y, q1.x, p4) FTOK(u2.z, u2.w, q1.y, p5)
    FTOK(u3.x, u3.y, q1.z, p6) FTOK(u3.z, u3.w, q1.w, p7)
    if (lane == 63) {
      *(float4*)(po + it * 8) = make_float4(p0, p1, p2, p3);
      *(float4*)(po + it * 8 + 4) = make_float4(p4, p5, p6, p7);
    }
  }
}

extern "C" void kernel_launch(void* const* d_in, const int* in_sizes, int n_in,
                              void* d_out, int out_size, void* d_ws, size_t ws_size,
                              hipStream_t stream) {
  const float* x         = (const float*)d_in[0];
  const float* in_proj_w = (const float*)d_in[1];
  const float* conv_w    = (const float*)d_in[2];
  const float* conv_b    = (const float*)d_in[3];
  const float* x_proj_w  = (const float*)d_in[4];
  const float* dt_w      = (const float*)d_in[5];
  const float* dt_b      = (const float*)d_in[6];
  const float* A_log     = (const float*)d_in[7];
  const float* Dvec      = (const float*)d_in[8];
  const float* out_proj_w= (const float*)d_in[9];

  char* w = (char*)d_ws;
  __hip_bfloat16* Wt1 = (__hip_bfloat16*)w; w += (size_t)D_XZ * D_MODEL * 2;      // 8 MB
  __hip_bfloat16* Wt2 = (__hip_bfloat16*)w; w += (size_t)N_XP * D_INNER * 2;      // 516 KB
  __hip_bfloat16* Wt3 = (__hip_bfloat16*)w; w += (size_t)D_MODEL * D_INNER * 2;   // 4 MB
  __hip_bfloat16* xb  = (__hip_bfloat16*)w; w += (size_t)N_TOK * D_MODEL * 2;     // 2 MB
  float*          xzf = (float*)w;          w += (size_t)N_TOK * D_XZ * 4;        // 16 MB
  float*          xc  = (float*)w;          w += (size_t)N_TOK * D_INNER * 4;     // 8 MB
  __hip_bfloat16* xcb = (__hip_bfloat16*)w; w += (size_t)N_TOK * D_INNER * 2;     // 4 MB
  float*          P   = (float*)w;          w += (size_t)16 * N_TOK * N_XP * 4;   // 8.45 MB
  unsigned int*   bc8 = (unsigned int*)w;   w += (size_t)N_TOK * D_STATE * 4;     // 256 KB
  float*          dtr = (float*)w;          w += (size_t)N_TOK * 4;               // 4 KB
  float2*         uaT = (float2*)w;         w += (size_t)D_INNER * N_TOK * 8;     // 16 MB
  unsigned int*   ug2 = (unsigned int*)w;   w += (size_t)N_TOK * D_INNER * 4;     // 8 MB
  // aliases (lifetimes):
  float*          praw = P;            // 8 MB <= 8.45 MB; P dead after reduce_bc
  __hip_bfloat16* ybb  = xcb;          // 4 MB; xcb dead after gemm2
  float*          Pg   = xzf;          // 16 MB; xzf dead after pack

  float* out       = (float*)d_out;
  float* state_out = out + (size_t)N_TOK * D_MODEL;

  dim3 blk(256);
  transpose_bf16<<<dim3(D_XZ / 64, D_MODEL / 64), blk, 0, stream>>>(in_proj_w, Wt1, D_MODEL, D_XZ);
  transpose_bf16<<<dim3((N_XP + 63) / 64, D_INNER / 64), blk, 0, stream>>>(x_proj_w, Wt2, D_INNER, N_XP);
  transpose_bf16<<<dim3(D_MODEL / 64, D_INNER / 64), blk, 0, stream>>>(out_proj_w, Wt3, D_INNER, D_MODEL);
  convert_bf16<<<(N_TOK * D_MODEL) / 256, blk, 0, stream>>>(x, xb, N_TOK * D_MODEL);
  // 1) xz = x @ in_proj_w  (BM=64: 32x16 = 512 blocks)
  gemm_bf16_tn<64><<<dim3(D_XZ / 128, N_TOK / 64), blk, 0, stream>>>(xb, Wt1, xzf, N_TOK, D_XZ, D_MODEL);
  // 2) conv + silu
  conv_silu_kernel<<<(N_TOK * D_INNER) / 256, blk, 0, stream>>>(xzf, conv_w, conv_b, xc, xcb);
  // 3) xp partials: split-K x16 (BM=64)
  gemm_splitk<64><<<dim3((N_XP + 127) / 128, N_TOK / 64, 16), blk, 0, stream>>>(xcb, Wt2, P, N_TOK, N_XP, D_INNER, 128);
  // 4) reduce -> bc8 + dtr
  reduce_bc<<<N_TOK / 4, blk, 0, stream>>>(P, bc8, dtr);
  // 5) pack streams
  pack_kernel<<<dim3(N_TOK / 32, D_INNER / 64), blk, 0, stream>>>(xzf, xc, dtr, dt_w, dt_b, Dvec, uaT, ug2);
  // 6) fused chunked scan
  scan_fused<<<2 * D_INNER, blk, 0, stream>>>(uaT, bc8, A_log, praw, state_out);
  // 7) gate (transpose praw [d][tok] -> ybb [tok][d])
  gate_kernel<<<dim3(N_TOK / 64, D_INNER / 64), blk, 0, stream>>>(praw, ug2, ybb);
  // 8) out = y @ out_proj_w : split-K x4 (BM=64) + reduce
  gemm_splitk<64><<<dim3(D_MODEL / 128, N_TOK / 64, 4), blk, 0, stream>>>(ybb, Wt3, Pg, N_TOK, D_MODEL, D_INNER, 512);
  reduce_z<4><<<(N_TOK * D_MODEL) / 1024, blk, 0, stream>>>(Pg, out, N_TOK * D_MODEL);
}

// Round 10
// 300.385 us; speedup vs baseline: 1.2872x; 1.0462x over previous
//
#include <hip/hip_runtime.h>
#include <hip/hip_bf16.h>

// Mamba block on MI355X. B=2, L=512, d_model=1024, d_inner=2048, d_state=64, K=4.
// Pipeline:
//   transpose x3 : weights -> bf16 [N][K]; convert x -> bf16
//   gemm1 : xzf[1024][4096] = xb @ Wt1^T   (MFMA bf16, BM=64 tile, 512 blocks)
//   conv  : xc = silu(causal depthwise conv(xs)) f32 + bf16 copy
//   gemm2 : split-K x16 partials of xcb @ Wt2^T -> P  (BM=64)
//   reduce_bc : P -> bcq[tok][ln] = f32x4 {B[n0],B[n1],C[n0],C[n1]} + dtr[tok]
//   pack  : uaT[d][tok]={dt,dt*x} f32x2 ; ug2[tok][d]=bf16x2{D*x,g}
//   scan_fused : block per (b,d); 4 waves x 2 half-waves = 8 chunks x 64 toks.
//                Each lane holds 2 states (n, n+32); half-wave = one chunk.
//                phase1 (P=prod dA, s_loc) -> LDS combine (8 chunks) -> phase2
//                (full recurrence + 5-op DPP 32-lane reduce; lanes 31/63 store).
//   gate  : LDS-transpose, ybb[tok][d] = bf16((praw + D*x) * g)
//   gemm3 : split-K x4 partials of ybb @ Wt3^T (BM=64) ; reduce_z -> out

#define N_TOK   1024
#define SEQ_L   512
#define D_MODEL 1024
#define D_INNER 2048
#define D_STATE 64
#define D_XZ    4096
#define N_XP    129

typedef __attribute__((ext_vector_type(8))) short bf16x8;
typedef __attribute__((ext_vector_type(4))) float f32x4;

__device__ __forceinline__ unsigned short f2bf(float f) {
  __hip_bfloat16 h = __float2bfloat16(f);
  return *reinterpret_cast<unsigned short*>(&h);
}
__device__ __forceinline__ float bf16lo(unsigned int u) { return __uint_as_float(u << 16); }
__device__ __forceinline__ float bf16hi(unsigned int u) { return __uint_as_float(u & 0xffff0000u); }

// ---------- transpose + f32->bf16 convert: dst[C][R] = bf16(src[R][C]) ----------
__global__ __launch_bounds__(256) void transpose_bf16(
    const float* __restrict__ src, __hip_bfloat16* __restrict__ dst, int R, int C) {
  __shared__ float t[64][65];
  int c0 = blockIdx.x * 64, r0 = blockIdx.y * 64;
  int tc = threadIdx.x & 63, tg = threadIdx.x >> 6;
#pragma unroll
  for (int i = 0; i < 16; ++i) {
    int r = r0 + tg + i * 4, c = c0 + tc;
    t[tg + i * 4][tc] = (r < R && c < C) ? src[(size_t)r * C + c] : 0.f;
  }
  __syncthreads();
#pragma unroll
  for (int i = 0; i < 16; ++i) {
    int c = c0 + tg + i * 4, r = r0 + tc;
    if (c < C && r < R) dst[(size_t)c * R + r] = __float2bfloat16(t[tc][tg + i * 4]);
  }
}

__global__ __launch_bounds__(256) void convert_bf16(
    const float* __restrict__ src, __hip_bfloat16* __restrict__ dst, int n) {
  int i = blockIdx.x * 256 + threadIdx.x;
  if (i < n) dst[i] = __float2bfloat16(src[i]);
}

// ---------- MFMA bf16 TN GEMM (full-K): C[M][N] = A[M][K] @ Bt[N][K]^T ----------
template<int BM>
__global__ __launch_bounds__(256) void gemm_bf16_tn(
    const __hip_bfloat16* __restrict__ A, const __hip_bfloat16* __restrict__ Bt,
    float* __restrict__ C, int M, int N, int K) {
  const int MF = BM / 32;
  __shared__ short As[BM][40];   // rows padded to 80 B
  __shared__ short Bs[128][40];
  const int brow = blockIdx.y * BM, bcol = blockIdx.x * 128;
  const int tid = threadIdx.x;
  const int lane = tid & 63, wave = tid >> 6;
  const int wm = wave >> 1, wn = wave & 1;
  const int l15 = lane & 15, lk = lane >> 4;
  f32x4 acc[MF][4] = {};
  for (int k0 = 0; k0 < K; k0 += 32) {
#pragma unroll
    for (int i = 0; i < BM / 64; ++i) {
      int v = tid + i * 256;
      int r = v >> 2, kc = (v & 3) * 8;
      *(bf16x8*)((char*)&As[0][0] + r * 80 + kc * 2) =
          *(const bf16x8*)&A[(size_t)(brow + r) * K + k0 + kc];
    }
#pragma unroll
    for (int i = 0; i < 2; ++i) {
      int v = tid + i * 256;
      int r = v >> 2, kc = (v & 3) * 8;
      *(bf16x8*)((char*)&Bs[0][0] + r * 80 + kc * 2) =
          *(const bf16x8*)&Bt[(size_t)(bcol + r) * K + k0 + kc];
    }
    __syncthreads();
    bf16x8 af[MF], bfr[4];
#pragma unroll
    for (int m = 0; m < MF; ++m)
      af[m] = *(const bf16x8*)((const char*)&As[0][0] + (wm * (BM / 2) + m * 16 + l15) * 80 + lk * 16);
#pragma unroll
    for (int n = 0; n < 4; ++n)
      bfr[n] = *(const bf16x8*)((const char*)&Bs[0][0] + (wn * 64 + n * 16 + l15) * 80 + lk * 16);
#pragma unroll
    for (int m = 0; m < MF; ++m)
#pragma unroll
      for (int n = 0; n < 4; ++n)
        acc[m][n] = __builtin_amdgcn_mfma_f32_16x16x32_bf16(af[m], bfr[n], acc[m][n], 0, 0, 0);
    __syncthreads();
  }
#pragma unroll
  for (int m = 0; m < MF; ++m) {
    int row = brow + wm * (BM / 2) + m * 16 + lk * 4;
#pragma unroll
    for (int n = 0; n < 4; ++n) {
      int col = bcol + wn * 64 + n * 16 + l15;
#pragma unroll
      for (int r = 0; r < 4; ++r)
        C[(size_t)(row + r) * N + col] = acc[m][n][r];
    }
  }
}

// ---------- split-K MFMA GEMM: P[z][M][N] partials ----------
template<int BM>
__global__ __launch_bounds__(256) void gemm_splitk(
    const __hip_bfloat16* __restrict__ A, const __hip_bfloat16* __restrict__ Bt,
    float* __restrict__ P, int M, int N, int K, int kchunk) {
  const int MF = BM / 32;
  __shared__ short As[BM][40];
  __shared__ short Bs[128][40];
  const int brow = blockIdx.y * BM, bcol = blockIdx.x * 128;
  const int kbase = blockIdx.z * kchunk;
  const int tid = threadIdx.x;
  const int lane = tid & 63, wave = tid >> 6;
  const int wm = wave >> 1, wn = wave & 1;
  const int l15 = lane & 15, lk = lane >> 4;
  f32x4 acc[MF][4] = {};
  for (int k0 = kbase; k0 < kbase + kchunk; k0 += 32) {
#pragma unroll
    for (int i = 0; i < BM / 64; ++i) {
      int v = tid + i * 256;
      int r = v >> 2, kc = (v & 3) * 8;
      *(bf16x8*)((char*)&As[0][0] + r * 80 + kc * 2) =
          *(const bf16x8*)&A[(size_t)(brow + r) * K + k0 + kc];
    }
#pragma unroll
    for (int i = 0; i < 2; ++i) {
      int v = tid + i * 256;
      int r = v >> 2, kc = (v & 3) * 8;
      bf16x8 bv = {};
      if ((bcol + r) < N)
        bv = *(const bf16x8*)&Bt[(size_t)(bcol + r) * K + k0 + kc];
      *(bf16x8*)((char*)&Bs[0][0] + r * 80 + kc * 2) = bv;
    }
    __syncthreads();
    bf16x8 af[MF], bfr[4];
#pragma unroll
    for (int m = 0; m < MF; ++m)
      af[m] = *(const bf16x8*)((const char*)&As[0][0] + (wm * (BM / 2) + m * 16 + l15) * 80 + lk * 16);
#pragma unroll
    for (int n = 0; n < 4; ++n)
      bfr[n] = *(const bf16x8*)((const char*)&Bs[0][0] + (wn * 64 + n * 16 + l15) * 80 + lk * 16);
#pragma unroll
    for (int m = 0; m < MF; ++m)
#pragma unroll
      for (int n = 0; n < 4; ++n)
        acc[m][n] = __builtin_amdgcn_mfma_f32_16x16x32_bf16(af[m], bfr[n], acc[m][n], 0, 0, 0);
    __syncthreads();
  }
  float* Pz = P + (size_t)blockIdx.z * M * N;
#pragma unroll
  for (int m = 0; m < MF; ++m) {
    int row = brow + wm * (BM / 2) + m * 16 + lk * 4;
#pragma unroll
    for (int n = 0; n < 4; ++n) {
      int col = bcol + wn * 64 + n * 16 + l15;
      if (col < N) {
#pragma unroll
        for (int r = 0; r < 4; ++r)
          Pz[(size_t)(row + r) * N + col] = acc[m][n][r];
      }
    }
  }
}

// ---------- reduce Z partials elementwise (vectorized x4) ----------
template<int Z>
__global__ __launch_bounds__(256) void reduce_z(
    const float* __restrict__ P, float* __restrict__ out, int n) {
  int i = (blockIdx.x * 256 + threadIdx.x) * 4;
  if (i >= n) return;
  float4 s = *(const float4*)&P[i];
#pragma unroll
  for (int z = 1; z < Z; ++z) {
    float4 v = *(const float4*)&P[(size_t)z * n + i];
    s.x += v.x; s.y += v.y; s.z += v.z; s.w += v.w;
  }
  *(float4*)&out[i] = s;
}

// ---------- reduce partials -> bcq[tok][ln] = {B[n0],B[n1],C[n0],C[n1]} + dtr ----------
__global__ __launch_bounds__(256) void reduce_bc(
    const float* __restrict__ P, float4* __restrict__ bcq,
    float* __restrict__ dtr) {
  int tok = blockIdx.x * 8 + (threadIdx.x >> 5);
  int ln = threadIdx.x & 31;
  const float* p0 = P + (size_t)tok * N_XP;
  float b0 = 0.f, b1 = 0.f, c0 = 0.f, c1 = 0.f;
#pragma unroll
  for (int z = 0; z < 16; ++z) {
    const float* pz = p0 + (size_t)z * N_TOK * N_XP;
    b0 += pz[ln]; b1 += pz[ln + 32];
    c0 += pz[64 + ln]; c1 += pz[64 + ln + 32];
  }
  bcq[(size_t)tok * 32 + ln] = make_float4(b0, b1, c0, c1);
  if (ln == 0) {
    float sd = 0.f;
    const float* pd = p0 + 128;
#pragma unroll
    for (int z = 0; z < 16; ++z) sd += pd[(size_t)z * N_TOK * N_XP];
    dtr[tok] = sd;
  }
}

// ---------- causal depthwise conv (K=4) + SiLU ----------
__global__ __launch_bounds__(256) void conv_silu_kernel(
    const float* __restrict__ xz, const float* __restrict__ cw,
    const float* __restrict__ cb, float* __restrict__ xc,
    __hip_bfloat16* __restrict__ xcb) {
  int idx = blockIdx.x * 256 + threadIdx.x;
  int c = idx & (D_INNER - 1);
  int tok = idx >> 11;
  int l = tok & (SEQ_L - 1);
  float acc = cb[c];
#pragma unroll
  for (int k = 0; k < 4; ++k) {
    int ll = l - 3 + k;
    if (ll >= 0) acc = fmaf(xz[(size_t)(tok - 3 + k) * D_XZ + c], cw[c * 4 + k], acc);
  }
  float v = acc / (1.f + __expf(-acc));
  xc[idx] = v;
  xcb[idx] = __float2bfloat16(v);
}

// ---------- pack: uaT[d][tok]={dt,dt*x} (LDS transpose); ug2[tok][d]={Dx,g} ----------
__global__ __launch_bounds__(256) void pack_kernel(
    const float* __restrict__ xzf, const float* __restrict__ xc,
    const float* __restrict__ dtr, const float* __restrict__ dt_w,
    const float* __restrict__ dt_b, const float* __restrict__ Dv,
    float2* __restrict__ uaT, unsigned int* __restrict__ ug2) {
  __shared__ float2 la[64][33];
  int tok0 = blockIdx.x * 32, d0 = blockIdx.y * 64;
  int t = threadIdx.x;
  int dl = t & 63, tc = t >> 6;
  int d = d0 + dl;
  float w = dt_w[d], bb = dt_b[d], Dd = Dv[d];
#pragma unroll
  for (int p = 0; p < 8; ++p) {
    int tl = p * 4 + tc;
    int tok = tok0 + tl;
    float xt = xc[(size_t)tok * D_INNER + d];
    float z = xzf[(size_t)tok * D_XZ + D_INNER + d];
    float dt = dtr[tok] * w + bb;
    dt = (dt > 20.f) ? dt : log1pf(__expf(dt));
    la[dl][tl] = make_float2(dt, dt * xt);
    float g = z / (1.f + __expf(-z));
    ug2[(size_t)tok * D_INNER + d] =
        (unsigned int)f2bf(Dd * xt) | ((unsigned int)f2bf(g) << 16);
  }
  __syncthreads();
  int tl2 = t & 31, dg = t >> 5;
#pragma unroll
  for (int q = 0; q < 8; ++q) {
    int dl2 = q * 8 + dg;
    uaT[(size_t)(d0 + dl2) * N_TOK + tok0 + tl2] = la[dl2][tl2];
  }
}

// ---------- gate w/ LDS transpose: ybb[tok][d] = bf16((praw[d][tok] + Dx)*g) ----------
__global__ __launch_bounds__(256) void gate_kernel(
    const float* __restrict__ praw, const unsigned int* __restrict__ ug2,
    __hip_bfloat16* __restrict__ ybb) {
  __shared__ float tile[64][65];
  int tok0 = blockIdx.x * 64, d0 = blockIdx.y * 64;
  int t = threadIdx.x, tc = t & 63, tg = t >> 6;
#pragma unroll
  for (int i = 0; i < 16; ++i) {
    int dl = tg + i * 4;
    tile[dl][tc] = praw[(size_t)(d0 + dl) * N_TOK + tok0 + tc];
  }
  __syncthreads();
#pragma unroll
  for (int i = 0; i < 16; ++i) {
    int tl = tg + i * 4;
    size_t idx = (size_t)(tok0 + tl) * D_INNER + d0 + tc;
    unsigned u = ug2[idx];
    float v = (tile[tc][tl] + bf16lo(u)) * bf16hi(u);
    ybb[idx] = __float2bfloat16(v);
  }
}

// ---------- DPP 32-lane sum (builtin; folds to v_add_f32_dpp).
// Result valid in lanes 31 and 63 (independent half-wave sums). ----------
template<int CTRL>
__device__ __forceinline__ float dppadd(float v) {
  int t = __builtin_amdgcn_update_dpp(0, __float_as_int(v), CTRL, 0xF, 0xF, true);
  return v + __int_as_float(t);
}
__device__ __forceinline__ float wave_sum32(float v) {
  v = dppadd<0x111>(v);  // row_shr:1
  v = dppadd<0x112>(v);  // row_shr:2
  v = dppadd<0x114>(v);  // row_shr:4
  v = dppadd<0x118>(v);  // row_shr:8
  v = dppadd<0x142>(v);  // row_bcast:15
  return v;
}

// ---------- fused chunked scan: block = (b,d); 8 chunks = 4 waves x 2 halves ----
// Lane holds states n0=ln, n1=ln+32 in 2 regs. dt is token-scalar (shared).
// a2 = -exp(A_log) * log2(e); dA = exp2(dt * a2).
__global__ __launch_bounds__(256) void scan_fused(
    const float2* __restrict__ uaT, const float4* __restrict__ bcq,
    const float* __restrict__ A_log, float* __restrict__ praw,
    float* __restrict__ state_out) {
  __shared__ float lP[8][64], lS[8][64];
  int bd = blockIdx.x;                      // b*2048 + d
  int d = bd & (D_INNER - 1), b = bd >> 11;
  int tid = threadIdx.x;
  int wave = tid >> 6, lane = tid & 63;
  int h = lane >> 5, ln = lane & 31;
  int ch = wave * 2 + h;                    // chunk 0..7, 64 tokens each
  int n0 = ln, n1 = ln + 32;
  const float LOG2E = 1.4426950408889634f;
  float a2_0 = -__expf(A_log[d * D_STATE + n0]) * LOG2E;
  float a2_1 = -__expf(A_log[d * D_STATE + n1]) * LOG2E;
  int tok0 = b * SEQ_L + ch * 64;
  const float2* u0 = uaT + (size_t)d * N_TOK + tok0;
  const float4* q0 = bcq + (size_t)tok0 * 32 + ln;

  // ---- phase 1: local scan (decay product + local state) ----
  float s0 = 0.f, s1 = 0.f, P0 = 1.f, P1 = 1.f;
  {
    const float2* u = u0; const float4* q = q0;
#pragma unroll 1
    for (int t8 = 0; t8 < 8; ++t8) {
#pragma unroll
      for (int j = 0; j < 8; ++j) {
        float2 uv = u[j];
        float4 qv = q[j * 32];
        float dA0 = exp2f(uv.x * a2_0);
        float dA1 = exp2f(uv.x * a2_1);
        P0 *= dA0; P1 *= dA1;
        s0 = fmaf(dA0, s0, uv.y * qv.x);
        s1 = fmaf(dA1, s1, uv.y * qv.y);
      }
      u += 8; q += 256;
    }
  }
  lP[ch][n0] = P0; lP[ch][n1] = P1;
  lS[ch][n0] = s0; lS[ch][n1] = s1;
  __syncthreads();
  // ---- combine: chain chunks 0..ch-1 ----
  float si0 = 0.f, si1 = 0.f;
#pragma unroll
  for (int c = 0; c < 7; ++c) {
    if (c < ch) {
      si0 = fmaf(lP[c][n0], si0, lS[c][n0]);
      si1 = fmaf(lP[c][n1], si1, lS[c][n1]);
    }
  }
  if (ch == 7) {
    state_out[(size_t)bd * D_STATE + n0] = fmaf(P0, si0, s0);
    state_out[(size_t)bd * D_STATE + n1] = fmaf(P1, si1, s1);
  }

  // ---- phase 2: full recurrence + 32-lane DPP reduce ----
  s0 = si0; s1 = si1;
  {
    const float2* u = u0; const float4* q = q0;
    float* po = praw + (size_t)d * N_TOK + tok0;
#pragma unroll 1
    for (int t8 = 0; t8 < 8; ++t8) {
      float pb[8];
#pragma unroll
      for (int j = 0; j < 8; ++j) {
        float2 uv = u[j];
        float4 qv = q[j * 32];
        float dA0 = exp2f(uv.x * a2_0);
        float dA1 = exp2f(uv.x * a2_1);
        s0 = fmaf(dA0, s0, uv.y * qv.x);
        s1 = fmaf(dA1, s1, uv.y * qv.y);
        float p = s0 * qv.z;
        p = fmaf(s1, qv.w, p);
        pb[j] = wave_sum32(p);
      }
      if (ln == 31) {   // lanes 31 (chunk 2w) and 63 (chunk 2w+1)
        *(float4*)(po + t8 * 8) = make_float4(pb[0], pb[1], pb[2], pb[3]);
        *(float4*)(po + t8 * 8 + 4) = make_float4(pb[4], pb[5], pb[6], pb[7]);
      }
      u += 8; q += 256;
    }
  }
}

extern "C" void kernel_launch(void* const* d_in, const int* in_sizes, int n_in,
                              void* d_out, int out_size, void* d_ws, size_t ws_size,
                              hipStream_t stream) {
  const float* x         = (const float*)d_in[0];
  const float* in_proj_w = (const float*)d_in[1];
  const float* conv_w    = (const float*)d_in[2];
  const float* conv_b    = (const float*)d_in[3];
  const float* x_proj_w  = (const float*)d_in[4];
  const float* dt_w      = (const float*)d_in[5];
  const float* dt_b      = (const float*)d_in[6];
  const float* A_log     = (const float*)d_in[7];
  const float* Dvec      = (const float*)d_in[8];
  const float* out_proj_w= (const float*)d_in[9];

  char* w = (char*)d_ws;
  __hip_bfloat16* Wt1 = (__hip_bfloat16*)w; w += (size_t)D_XZ * D_MODEL * 2;      // 8 MB
  __hip_bfloat16* Wt2 = (__hip_bfloat16*)w; w += (size_t)N_XP * D_INNER * 2;      // 516 KB
  __hip_bfloat16* Wt3 = (__hip_bfloat16*)w; w += (size_t)D_MODEL * D_INNER * 2;   // 4 MB
  __hip_bfloat16* xb  = (__hip_bfloat16*)w; w += (size_t)N_TOK * D_MODEL * 2;     // 2 MB
  float*          xzf = (float*)w;          w += (size_t)N_TOK * D_XZ * 4;        // 16 MB
  float*          xc  = (float*)w;          w += (size_t)N_TOK * D_INNER * 4;     // 8 MB
  __hip_bfloat16* xcb = (__hip_bfloat16*)w; w += (size_t)N_TOK * D_INNER * 2;     // 4 MB
  float*          P   = (float*)w;          w += (size_t)16 * N_TOK * N_XP * 4;   // 8.45 MB
  float4*         bcq = (float4*)w;         w += (size_t)N_TOK * 32 * 16;         // 512 KB
  float*          dtr = (float*)w;          w += (size_t)N_TOK * 4;               // 4 KB
  float2*         uaT = (float2*)w;         w += (size_t)D_INNER * N_TOK * 8;     // 16 MB
  unsigned int*   ug2 = (unsigned int*)w;   w += (size_t)N_TOK * D_INNER * 4;     // 8 MB
  // aliases (lifetimes):
  float*          praw = P;            // 8 MB <= 8.45 MB; P dead after reduce_bc
  __hip_bfloat16* ybb  = xcb;          // 4 MB; xcb dead after gemm2
  float*          Pg   = xzf;          // 16 MB; xzf dead after pack

  float* out       = (float*)d_out;
  float* state_out = out + (size_t)N_TOK * D_MODEL;

  dim3 blk(256);
  transpose_bf16<<<dim3(D_XZ / 64, D_MODEL / 64), blk, 0, stream>>>(in_proj_w, Wt1, D_MODEL, D_XZ);
  transpose_bf16<<<dim3((N_XP + 63) / 64, D_INNER / 64), blk, 0, stream>>>(x_proj_w, Wt2, D_INNER, N_XP);
  transpose_bf16<<<dim3(D_MODEL / 64, D_INNER / 64), blk, 0, stream>>>(out_proj_w, Wt3, D_INNER, D_MODEL);
  convert_bf16<<<(N_TOK * D_MODEL) / 256, blk, 0, stream>>>(x, xb, N_TOK * D_MODEL);
  // 1) xz = x @ in_proj_w  (BM=64: 32x16 = 512 blocks)
  gemm_bf16_tn<64><<<dim3(D_XZ / 128, N_TOK / 64), blk, 0, stream>>>(xb, Wt1, xzf, N_TOK, D_XZ, D_MODEL);
  // 2) conv + silu
  conv_silu_kernel<<<(N_TOK * D_INNER) / 256, blk, 0, stream>>>(xzf, conv_w, conv_b, xc, xcb);
  // 3) xp partials: split-K x16 (BM=64)
  gemm_splitk<64><<<dim3((N_XP + 127) / 128, N_TOK / 64, 16), blk, 0, stream>>>(xcb, Wt2, P, N_TOK, N_XP, D_INNER, 128);
  // 4) reduce -> bcq (f32 quad) + dtr
  reduce_bc<<<N_TOK / 8, blk, 0, stream>>>(P, bcq, dtr);
  // 5) pack streams
  pack_kernel<<<dim3(N_TOK / 32, D_INNER / 64), blk, 0, stream>>>(xzf, xc, dtr, dt_w, dt_b, Dvec, uaT, ug2);
  // 6) fused chunked scan (2 states/lane, 8 chunks)
  scan_fused<<<2 * D_INNER, blk, 0, stream>>>(uaT, bcq, A_log, praw, state_out);
  // 7) gate (transpose praw [d][tok] -> ybb [tok][d])
  gate_kernel<<<dim3(N_TOK / 64, D_INNER / 64), blk, 0, stream>>>(praw, ug2, ybb);
  // 8) out = y @ out_proj_w : split-K x4 (BM=64) + reduce
  gemm_splitk<64><<<dim3(D_MODEL / 128, N_TOK / 64, 4), blk, 0, stream>>>(ybb, Wt3, Pg, N_TOK, D_MODEL, D_INNER, 512);
  reduce_z<4><<<(N_TOK * D_MODEL) / 1024, blk, 0, stream>>>(Pg, out, N_TOK * D_MODEL);
}

// Round 11
// 270.136 us; speedup vs baseline: 1.4314x; 1.1120x over previous
//
#include <hip/hip_runtime.h>
#include <hip/hip_bf16.h>

// Mamba block on MI355X. B=2, L=512, d_model=1024, d_inner=2048, d_state=64, K=4.
// Pipeline:
//   prep  : 1 kernel = transpose x3 (weights -> bf16 [N][K]) + convert x -> bf16
//   gemm1 : xzf[1024][4096] = xb @ Wt1^T   (MFMA bf16, BM=64 tile, 512 blocks)
//   conv  : xc = silu(causal depthwise conv(xs)) f32 + bf16 copy
//   gemm2 : split-K x16 partials of xcb @ Wt2^T -> P  (BM=64)
//   reduce_bc : P -> Bq[tok][lq]={B[n],B[n+16],B[n+32],B[n+48]}, Cq likewise + dtr
//   pack  : uaT[d][tok]={dt,dt*x} f32x2 ; ug2[tok][d]=bf16x2{D*x,g}
//   scan_fused : block per (b,d); 4 waves x 4 quarter-waves = 16 chunks x 32 toks.
//                Lane holds 4 states (lq, lq+16, lq+32, lq+48); quarter = chunk.
//                phase1 (P=prod dA, s_loc; reads Bq only) -> LDS combine (16) ->
//                phase2 (recurrence + 4-op 16-lane DPP reduce; lanes 15/31/47/63).
//   gate  : LDS-transpose, ybb[tok][d] = bf16((praw + D*x) * g)
//   gemm3 : split-K x4 partials of ybb @ Wt3^T (BM=64) ; reduce_z -> out

#define N_TOK   1024
#define SEQ_L   512
#define D_MODEL 1024
#define D_INNER 2048
#define D_STATE 64
#define D_XZ    4096
#define N_XP    129

typedef __attribute__((ext_vector_type(8))) short bf16x8;
typedef __attribute__((ext_vector_type(4))) float f32x4;

__device__ __forceinline__ unsigned short f2bf(float f) {
  __hip_bfloat16 h = __float2bfloat16(f);
  return *reinterpret_cast<unsigned short*>(&h);
}
__device__ __forceinline__ float bf16lo(unsigned int u) { return __uint_as_float(u << 16); }
__device__ __forceinline__ float bf16hi(unsigned int u) { return __uint_as_float(u & 0xffff0000u); }

// ---------- prep: 3 weight transposes (f32 -> bf16 [N][K]) + x convert ----------
// tiles: job0 [0,1024): in_proj 1024x4096 (cx=64); job1 [1024,1120): x_proj
// 2048x129 (cx=3); job2 [1120,1632): out_proj 2048x1024 (cx=16);
// job3 [1632,1696): convert x (64 blocks x 16384 elems).
__global__ __launch_bounds__(256) void prep_kernel(
    const float* __restrict__ w1, const float* __restrict__ w2,
    const float* __restrict__ w3, const float* __restrict__ x,
    __hip_bfloat16* __restrict__ Wt1, __hip_bfloat16* __restrict__ Wt2,
    __hip_bfloat16* __restrict__ Wt3, __hip_bfloat16* __restrict__ xb) {
  int bid = blockIdx.x;
  if (bid >= 1632) {
    int base = (bid - 1632) * 16384 + threadIdx.x * 4;
#pragma unroll
    for (int p = 0; p < 16; ++p) {
      int i = base + p * 1024;
      float4 v = *(const float4*)&x[i];
      unsigned lo = (unsigned)f2bf(v.x) | ((unsigned)f2bf(v.y) << 16);
      unsigned hi = (unsigned)f2bf(v.z) | ((unsigned)f2bf(v.w) << 16);
      *(uint2*)&xb[i] = make_uint2(lo, hi);
    }
    return;
  }
  __shared__ float t[64][65];
  const float* src; __hip_bfloat16* dst; int R, C, cx, t0;
  if (bid < 1024)      { src = w1; dst = Wt1; R = D_MODEL; C = D_XZ;   cx = 64; t0 = bid; }
  else if (bid < 1120) { src = w2; dst = Wt2; R = D_INNER; C = N_XP;   cx = 3;  t0 = bid - 1024; }
  else                 { src = w3; dst = Wt3; R = D_INNER; C = D_MODEL; cx = 16; t0 = bid - 1120; }
  int c0 = (t0 % cx) * 64, r0 = (t0 / cx) * 64;
  int tc = threadIdx.x & 63, tg = threadIdx.x >> 6;
#pragma unroll
  for (int i = 0; i < 16; ++i) {
    int r = r0 + tg + i * 4, c = c0 + tc;
    t[tg + i * 4][tc] = (r < R && c < C) ? src[(size_t)r * C + c] : 0.f;
  }
  __syncthreads();
#pragma unroll
  for (int i = 0; i < 16; ++i) {
    int c = c0 + tg + i * 4, r = r0 + tc;
    if (c < C && r < R) dst[(size_t)c * R + r] = __float2bfloat16(t[tc][tg + i * 4]);
  }
}

// ---------- MFMA bf16 TN GEMM (full-K): C[M][N] = A[M][K] @ Bt[N][K]^T ----------
template<int BM>
__global__ __launch_bounds__(256) void gemm_bf16_tn(
    const __hip_bfloat16* __restrict__ A, const __hip_bfloat16* __restrict__ Bt,
    float* __restrict__ C, int M, int N, int K) {
  const int MF = BM / 32;
  __shared__ short As[BM][40];   // rows padded to 80 B
  __shared__ short Bs[128][40];
  const int brow = blockIdx.y * BM, bcol = blockIdx.x * 128;
  const int tid = threadIdx.x;
  const int lane = tid & 63, wave = tid >> 6;
  const int wm = wave >> 1, wn = wave & 1;
  const int l15 = lane & 15, lk = lane >> 4;
  f32x4 acc[MF][4] = {};
  for (int k0 = 0; k0 < K; k0 += 32) {
#pragma unroll
    for (int i = 0; i < BM / 64; ++i) {
      int v = tid + i * 256;
      int r = v >> 2, kc = (v & 3) * 8;
      *(bf16x8*)((char*)&As[0][0] + r * 80 + kc * 2) =
          *(const bf16x8*)&A[(size_t)(brow + r) * K + k0 + kc];
    }
#pragma unroll
    for (int i = 0; i < 2; ++i) {
      int v = tid + i * 256;
      int r = v >> 2, kc = (v & 3) * 8;
      *(bf16x8*)((char*)&Bs[0][0] + r * 80 + kc * 2) =
          *(const bf16x8*)&Bt[(size_t)(bcol + r) * K + k0 + kc];
    }
    __syncthreads();
    bf16x8 af[MF], bfr[4];
#pragma unroll
    for (int m = 0; m < MF; ++m)
      af[m] = *(const bf16x8*)((const char*)&As[0][0] + (wm * (BM / 2) + m * 16 + l15) * 80 + lk * 16);
#pragma unroll
    for (int n = 0; n < 4; ++n)
      bfr[n] = *(const bf16x8*)((const char*)&Bs[0][0] + (wn * 64 + n * 16 + l15) * 80 + lk * 16);
#pragma unroll
    for (int m = 0; m < MF; ++m)
#pragma unroll
      for (int n = 0; n < 4; ++n)
        acc[m][n] = __builtin_amdgcn_mfma_f32_16x16x32_bf16(af[m], bfr[n], acc[m][n], 0, 0, 0);
    __syncthreads();
  }
#pragma unroll
  for (int m = 0; m < MF; ++m) {
    int row = brow + wm * (BM / 2) + m * 16 + lk * 4;
#pragma unroll
    for (int n = 0; n < 4; ++n) {
      int col = bcol + wn * 64 + n * 16 + l15;
#pragma unroll
      for (int r = 0; r < 4; ++r)
        C[(size_t)(row + r) * N + col] = acc[m][n][r];
    }
  }
}

// ---------- split-K MFMA GEMM: P[z][M][N] partials ----------
template<int BM>
__global__ __launch_bounds__(256) void gemm_splitk(
    const __hip_bfloat16* __restrict__ A, const __hip_bfloat16* __restrict__ Bt,
    float* __restrict__ P, int M, int N, int K, int kchunk) {
  const int MF = BM / 32;
  __shared__ short As[BM][40];
  __shared__ short Bs[128][40];
  const int brow = blockIdx.y * BM, bcol = blockIdx.x * 128;
  const int kbase = blockIdx.z * kchunk;
  const int tid = threadIdx.x;
  const int lane = tid & 63, wave = tid >> 6;
  const int wm = wave >> 1, wn = wave & 1;
  const int l15 = lane & 15, lk = lane >> 4;
  f32x4 acc[MF][4] = {};
  for (int k0 = kbase; k0 < kbase + kchunk; k0 += 32) {
#pragma unroll
    for (int i = 0; i < BM / 64; ++i) {
      int v = tid + i * 256;
      int r = v >> 2, kc = (v & 3) * 8;
      *(bf16x8*)((char*)&As[0][0] + r * 80 + kc * 2) =
          *(const bf16x8*)&A[(size_t)(brow + r) * K + k0 + kc];
    }
#pragma unroll
    for (int i = 0; i < 2; ++i) {
      int v = tid + i * 256;
      int r = v >> 2, kc = (v & 3) * 8;
      bf16x8 bv = {};
      if ((bcol + r) < N)
        bv = *(const bf16x8*)&Bt[(size_t)(bcol + r) * K + k0 + kc];
      *(bf16x8*)((char*)&Bs[0][0] + r * 80 + kc * 2) = bv;
    }
    __syncthreads();
    bf16x8 af[MF], bfr[4];
#pragma unroll
    for (int m = 0; m < MF; ++m)
      af[m] = *(const bf16x8*)((const char*)&As[0][0] + (wm * (BM / 2) + m * 16 + l15) * 80 + lk * 16);
#pragma unroll
    for (int n = 0; n < 4; ++n)
      bfr[n] = *(const bf16x8*)((const char*)&Bs[0][0] + (wn * 64 + n * 16 + l15) * 80 + lk * 16);
#pragma unroll
    for (int m = 0; m < MF; ++m)
#pragma unroll
      for (int n = 0; n < 4; ++n)
        acc[m][n] = __builtin_amdgcn_mfma_f32_16x16x32_bf16(af[m], bfr[n], acc[m][n], 0, 0, 0);
    __syncthreads();
  }
  float* Pz = P + (size_t)blockIdx.z * M * N;
#pragma unroll
  for (int m = 0; m < MF; ++m) {
    int row = brow + wm * (BM / 2) + m * 16 + lk * 4;
#pragma unroll
    for (int n = 0; n < 4; ++n) {
      int col = bcol + wn * 64 + n * 16 + l15;
      if (col < N) {
#pragma unroll
        for (int r = 0; r < 4; ++r)
          Pz[(size_t)(row + r) * N + col] = acc[m][n][r];
      }
    }
  }
}

// ---------- reduce Z partials elementwise (vectorized x4) ----------
template<int Z>
__global__ __launch_bounds__(256) void reduce_z(
    const float* __restrict__ P, float* __restrict__ out, int n) {
  int i = (blockIdx.x * 256 + threadIdx.x) * 4;
  if (i >= n) return;
  float4 s = *(const float4*)&P[i];
#pragma unroll
  for (int z = 1; z < Z; ++z) {
    float4 v = *(const float4*)&P[(size_t)z * n + i];
    s.x += v.x; s.y += v.y; s.z += v.z; s.w += v.w;
  }
  *(float4*)&out[i] = s;
}

// ---------- reduce partials -> Bq/Cq[tok][lq] (f32 quads, 4 states) + dtr ----------
__global__ __launch_bounds__(256) void reduce_bc(
    const float* __restrict__ P, float4* __restrict__ Bq,
    float4* __restrict__ Cq, float* __restrict__ dtr) {
  int tok = blockIdx.x * 16 + (threadIdx.x >> 4);
  int lq = threadIdx.x & 15;
  const float* p0 = P + (size_t)tok * N_XP;
  float b0 = 0, b1 = 0, b2 = 0, b3 = 0, c0 = 0, c1 = 0, c2 = 0, c3 = 0;
#pragma unroll
  for (int z = 0; z < 16; ++z) {
    const float* pz = p0 + (size_t)z * N_TOK * N_XP;
    b0 += pz[lq];      b1 += pz[lq + 16]; b2 += pz[lq + 32]; b3 += pz[lq + 48];
    c0 += pz[64 + lq]; c1 += pz[80 + lq]; c2 += pz[96 + lq]; c3 += pz[112 + lq];
  }
  Bq[(size_t)tok * 16 + lq] = make_float4(b0, b1, b2, b3);
  Cq[(size_t)tok * 16 + lq] = make_float4(c0, c1, c2, c3);
  if (lq == 0) {
    float sd = 0.f;
#pragma unroll
    for (int z = 0; z < 16; ++z) sd += p0[(size_t)z * N_TOK * N_XP + 128];
    dtr[tok] = sd;
  }
}

// ---------- causal depthwise conv (K=4) + SiLU ----------
__global__ __launch_bounds__(256) void conv_silu_kernel(
    const float* __restrict__ xz, const float* __restrict__ cw,
    const float* __restrict__ cb, float* __restrict__ xc,
    __hip_bfloat16* __restrict__ xcb) {
  int idx = blockIdx.x * 256 + threadIdx.x;
  int c = idx & (D_INNER - 1);
  int tok = idx >> 11;
  int l = tok & (SEQ_L - 1);
  float acc = cb[c];
#pragma unroll
  for (int k = 0; k < 4; ++k) {
    int ll = l - 3 + k;
    if (ll >= 0) acc = fmaf(xz[(size_t)(tok - 3 + k) * D_XZ + c], cw[c * 4 + k], acc);
  }
  float v = acc / (1.f + __expf(-acc));
  xc[idx] = v;
  xcb[idx] = __float2bfloat16(v);
}

// ---------- pack: uaT[d][tok]={dt,dt*x} (LDS transpose); ug2[tok][d]={Dx,g} ----------
__global__ __launch_bounds__(256) void pack_kernel(
    const float* __restrict__ xzf, const float* __restrict__ xc,
    const float* __restrict__ dtr, const float* __restrict__ dt_w,
    const float* __restrict__ dt_b, const float* __restrict__ Dv,
    float2* __restrict__ uaT, unsigned int* __restrict__ ug2) {
  __shared__ float2 la[64][33];
  int tok0 = blockIdx.x * 32, d0 = blockIdx.y * 64;
  int t = threadIdx.x;
  int dl = t & 63, tc = t >> 6;
  int d = d0 + dl;
  float w = dt_w[d], bb = dt_b[d], Dd = Dv[d];
#pragma unroll
  for (int p = 0; p < 8; ++p) {
    int tl = p * 4 + tc;
    int tok = tok0 + tl;
    float xt = xc[(size_t)tok * D_INNER + d];
    float z = xzf[(size_t)tok * D_XZ + D_INNER + d];
    float dt = dtr[tok] * w + bb;
    dt = (dt > 20.f) ? dt : log1pf(__expf(dt));
    la[dl][tl] = make_float2(dt, dt * xt);
    float g = z / (1.f + __expf(-z));
    ug2[(size_t)tok * D_INNER + d] =
        (unsigned int)f2bf(Dd * xt) | ((unsigned int)f2bf(g) << 16);
  }
  __syncthreads();
  int tl2 = t & 31, dg = t >> 5;
#pragma unroll
  for (int q = 0; q < 8; ++q) {
    int dl2 = q * 8 + dg;
    uaT[(size_t)(d0 + dl2) * N_TOK + tok0 + tl2] = la[dl2][tl2];
  }
}

// ---------- gate w/ LDS transpose: ybb[tok][d] = bf16((praw[d][tok] + Dx)*g) ----------
__global__ __launch_bounds__(256) void gate_kernel(
    const float* __restrict__ praw, const unsigned int* __restrict__ ug2,
    __hip_bfloat16* __restrict__ ybb) {
  __shared__ float tile[64][65];
  int tok0 = blockIdx.x * 64, d0 = blockIdx.y * 64;
  int t = threadIdx.x, tc = t & 63, tg = t >> 6;
#pragma unroll
  for (int i = 0; i < 16; ++i) {
    int dl = tg + i * 4;
    tile[dl][tc] = praw[(size_t)(d0 + dl) * N_TOK + tok0 + tc];
  }
  __syncthreads();
#pragma unroll
  for (int i = 0; i < 16; ++i) {
    int tl = tg + i * 4;
    size_t idx = (size_t)(tok0 + tl) * D_INNER + d0 + tc;
    unsigned u = ug2[idx];
    float v = (tile[tc][tl] + bf16lo(u)) * bf16hi(u);
    ybb[idx] = __float2bfloat16(v);
  }
}

// ---------- 16-lane DPP sum (row_shr tree; row=16). Result in lane 15 of each
// 16-lane group (lanes 15/31/47/63). ----------
template<int CTRL>
__device__ __forceinline__ float dppadd(float v) {
  int t = __builtin_amdgcn_update_dpp(0, __float_as_int(v), CTRL, 0xF, 0xF, true);
  return v + __int_as_float(t);
}
__device__ __forceinline__ float qsum16(float v) {
  v = dppadd<0x111>(v);  // row_shr:1
  v = dppadd<0x112>(v);  // row_shr:2
  v = dppadd<0x114>(v);  // row_shr:4
  v = dppadd<0x118>(v);  // row_shr:8
  return v;
}

// ---------- fused chunked scan: block=(b,d); 16 chunks = 4 waves x 4 quarters --
// Lane holds 4 states (lq, lq+16, lq+32, lq+48); quarter-wave = one 32-tok chunk.
__global__ __launch_bounds__(256) void scan_fused(
    const float2* __restrict__ uaT, const float4* __restrict__ Bq,
    const float4* __restrict__ Cq, const float* __restrict__ A_log,
    float* __restrict__ praw, float* __restrict__ state_out) {
  __shared__ float lP[16][64], lS[16][64];
  int bd = blockIdx.x;                      // b*2048 + d
  int d = bd & (D_INNER - 1), b = bd >> 11;
  int tid = threadIdx.x;
  int wave = tid >> 6, lane = tid & 63;
  int qw = lane >> 4, lq = lane & 15;
  int ch = wave * 4 + qw;                   // chunk 0..15, 32 tokens each
  const float L2E = 1.4426950408889634f;
  float a20 = -__expf(A_log[d * D_STATE + lq]) * L2E;
  float a21 = -__expf(A_log[d * D_STATE + lq + 16]) * L2E;
  float a22 = -__expf(A_log[d * D_STATE + lq + 32]) * L2E;
  float a23 = -__expf(A_log[d * D_STATE + lq + 48]) * L2E;
  int tok0 = b * SEQ_L + ch * 32;
  const float2* u0 = uaT + (size_t)d * N_TOK + tok0;
  const float4* B0 = Bq + (size_t)tok0 * 16 + lq;
  const float4* C0 = Cq + (size_t)tok0 * 16 + lq;

  // ---- phase 1: local scan (decay products + local state); reads Bq only ----
  float s0 = 0, s1 = 0, s2 = 0, s3 = 0, P0 = 1, P1 = 1, P2 = 1, P3 = 1;
  {
    const float2* u = u0; const float4* pB = B0;
#pragma unroll 1
    for (int t8 = 0; t8 < 4; ++t8) {
#pragma unroll
      for (int j = 0; j < 8; ++j) {
        float2 uv = u[j];
        float4 bv = pB[j * 16];
        float e0 = exp2f(uv.x * a20), e1 = exp2f(uv.x * a21);
        float e2 = exp2f(uv.x * a22), e3 = exp2f(uv.x * a23);
        P0 *= e0; P1 *= e1; P2 *= e2; P3 *= e3;
        s0 = fmaf(e0, s0, uv.y * bv.x);
        s1 = fmaf(e1, s1, uv.y * bv.y);
        s2 = fmaf(e2, s2, uv.y * bv.z);
        s3 = fmaf(e3, s3, uv.y * bv.w);
      }
      u += 8; pB += 128;
    }
  }
  lP[ch][lq] = P0; lP[ch][lq + 16] = P1; lP[ch][lq + 32] = P2; lP[ch][lq + 48] = P3;
  lS[ch][lq] = s0; lS[ch][lq + 16] = s1; lS[ch][lq + 32] = s2; lS[ch][lq + 48] = s3;
  __syncthreads();
  // ---- combine: chain chunks 0..ch-1 ----
  float si0 = 0, si1 = 0, si2 = 0, si3 = 0;
#pragma unroll
  for (int c = 0; c < 15; ++c) {
    if (c < ch) {
      si0 = fmaf(lP[c][lq], si0, lS[c][lq]);
      si1 = fmaf(lP[c][lq + 16], si1, lS[c][lq + 16]);
      si2 = fmaf(lP[c][lq + 32], si2, lS[c][lq + 32]);
      si3 = fmaf(lP[c][lq + 48], si3, lS[c][lq + 48]);
    }
  }
  if (ch == 15) {
    state_out[(size_t)bd * D_STATE + lq]      = fmaf(P0, si0, s0);
    state_out[(size_t)bd * D_STATE + lq + 16] = fmaf(P1, si1, s1);
    state_out[(size_t)bd * D_STATE + lq + 32] = fmaf(P2, si2, s2);
    state_out[(size_t)bd * D_STATE + lq + 48] = fmaf(P3, si3, s3);
  }

  // ---- phase 2: full recurrence + 16-lane DPP reduce ----
  s0 = si0; s1 = si1; s2 = si2; s3 = si3;
  {
    const float2* u = u0; const float4* pB = B0; const float4* pC = C0;
    float* po = praw + (size_t)d * N_TOK + tok0;
#pragma unroll 1
    for (int t8 = 0; t8 < 4; ++t8) {
      float pb[8];
#pragma unroll
      for (int j = 0; j < 8; ++j) {
        float2 uv = u[j];
        float4 bv = pB[j * 16];
        float4 cv = pC[j * 16];
        float e0 = exp2f(uv.x * a20), e1 = exp2f(uv.x * a21);
        float e2 = exp2f(uv.x * a22), e3 = exp2f(uv.x * a23);
        s0 = fmaf(e0, s0, uv.y * bv.x);
        s1 = fmaf(e1, s1, uv.y * bv.y);
        s2 = fmaf(e2, s2, uv.y * bv.z);
        s3 = fmaf(e3, s3, uv.y * bv.w);
        float p = s0 * cv.x;
        p = fmaf(s1, cv.y, p);
        p = fmaf(s2, cv.z, p);
        p = fmaf(s3, cv.w, p);
        pb[j] = qsum16(p);
      }
      if (lq == 15) {
        *(float4*)(po + t8 * 8) = make_float4(pb[0], pb[1], pb[2], pb[3]);
        *(float4*)(po + t8 * 8 + 4) = make_float4(pb[4], pb[5], pb[6], pb[7]);
      }
      u += 8; pB += 128; pC += 128;
    }
  }
}

extern "C" void kernel_launch(void* const* d_in, const int* in_sizes, int n_in,
                              void* d_out, int out_size, void* d_ws, size_t ws_size,
                              hipStream_t stream) {
  const float* x         = (const float*)d_in[0];
  const float* in_proj_w = (const float*)d_in[1];
  const float* conv_w    = (const float*)d_in[2];
  const float* conv_b    = (const float*)d_in[3];
  const float* x_proj_w  = (const float*)d_in[4];
  const float* dt_w      = (const float*)d_in[5];
  const float* dt_b      = (const float*)d_in[6];
  const float* A_log     = (const float*)d_in[7];
  const float* Dvec      = (const float*)d_in[8];
  const float* out_proj_w= (const float*)d_in[9];

  char* w = (char*)d_ws;
  __hip_bfloat16* Wt1 = (__hip_bfloat16*)w; w += (size_t)D_XZ * D_MODEL * 2;      // 8 MB
  __hip_bfloat16* Wt2 = (__hip_bfloat16*)w; w += (size_t)N_XP * D_INNER * 2;      // 516 KB
  __hip_bfloat16* Wt3 = (__hip_bfloat16*)w; w += (size_t)D_MODEL * D_INNER * 2;   // 4 MB
  __hip_bfloat16* xb  = (__hip_bfloat16*)w; w += (size_t)N_TOK * D_MODEL * 2;     // 2 MB
  float*          xzf = (float*)w;          w += (size_t)N_TOK * D_XZ * 4;        // 16 MB
  float*          xc  = (float*)w;          w += (size_t)N_TOK * D_INNER * 4;     // 8 MB
  __hip_bfloat16* xcb = (__hip_bfloat16*)w; w += (size_t)N_TOK * D_INNER * 2;     // 4 MB
  float*          P   = (float*)w;          w += (size_t)16 * N_TOK * N_XP * 4;   // 8.45 MB
  float4*         Bq  = (float4*)w;         w += (size_t)N_TOK * 16 * 16;         // 256 KB
  float4*         Cq  = (float4*)w;         w += (size_t)N_TOK * 16 * 16;         // 256 KB
  float*          dtr = (float*)w;          w += (size_t)N_TOK * 4;               // 4 KB
  float2*         uaT = (float2*)w;         w += (size_t)D_INNER * N_TOK * 8;     // 16 MB
  unsigned int*   ug2 = (unsigned int*)w;   w += (size_t)N_TOK * D_INNER * 4;     // 8 MB
  // aliases (lifetimes):
  float*          praw = P;            // 8 MB <= 8.45 MB; P dead after reduce_bc
  __hip_bfloat16* ybb  = xcb;          // 4 MB; xcb dead after gemm2
  float*          Pg   = xzf;          // 16 MB; xzf dead after pack

  float* out       = (float*)d_out;
  float* state_out = out + (size_t)N_TOK * D_MODEL;

  dim3 blk(256);
  // 0) prep: 3 transposes + x convert in one launch
  prep_kernel<<<1696, blk, 0, stream>>>(in_proj_w, x_proj_w, out_proj_w, x,
                                        Wt1, Wt2, Wt3, xb);
  // 1) xz = x @ in_proj_w  (BM=64: 32x16 = 512 blocks)
  gemm_bf16_tn<64><<<dim3(D_XZ / 128, N_TOK / 64), blk, 0, stream>>>(xb, Wt1, xzf, N_TOK, D_XZ, D_MODEL);
  // 2) conv + silu
  conv_silu_kernel<<<(N_TOK * D_INNER) / 256, blk, 0, stream>>>(xzf, conv_w, conv_b, xc, xcb);
  // 3) xp partials: split-K x16 (BM=64)
  gemm_splitk<64><<<dim3((N_XP + 127) / 128, N_TOK / 64, 16), blk, 0, stream>>>(xcb, Wt2, P, N_TOK, N_XP, D_INNER, 128);
  // 4) reduce -> Bq/Cq quads + dtr
  reduce_bc<<<N_TOK / 16, blk, 0, stream>>>(P, Bq, Cq, dtr);
  // 5) pack streams
  pack_kernel<<<dim3(N_TOK / 32, D_INNER / 64), blk, 0, stream>>>(xzf, xc, dtr, dt_w, dt_b, Dvec, uaT, ug2);
  // 6) fused chunked scan (4 states/lane, 16 chunks)
  scan_fused<<<2 * D_INNER, blk, 0, stream>>>(uaT, Bq, Cq, A_log, praw, state_out);
  // 7) gate (transpose praw [d][tok] -> ybb [tok][d])
  gate_kernel<<<dim3(N_TOK / 64, D_INNER / 64), blk, 0, stream>>>(praw, ug2, ybb);
  // 8) out = y @ out_proj_w : split-K x4 (BM=64) + reduce
  gemm_splitk<64><<<dim3(D_MODEL / 128, N_TOK / 64, 4), blk, 0, stream>>>(ybb, Wt3, Pg, N_TOK, D_MODEL, D_INNER, 512);
  reduce_z<4><<<(N_TOK * D_MODEL) / 1024, blk, 0, stream>>>(Pg, out, N_TOK * D_MODEL);
}